// Round 2
// baseline (1277.863 us; speedup 1.0000x reference)
//
#include <hip/hip_runtime.h>
#include <stdint.h>

#define JAX_PARTITIONABLE 1
#define NB 512

// ---------- helpers ----------
__device__ __forceinline__ float tanh_f(float x) {
  float e = __expf(2.0f * x);
  return 1.0f - 2.0f / (e + 1.0f);
}
__device__ __forceinline__ float sigm(float x) {
  return 1.0f / (1.0f + __expf(-x));
}

// ---------- Threefry-2x32 (JAX-compatible) ----------
__device__ __forceinline__ void tf2x32(unsigned k0, unsigned k1, unsigned x0, unsigned x1,
                                       unsigned &o0, unsigned &o1) {
  unsigned ks0 = k0, ks1 = k1, ks2 = k0 ^ k1 ^ 0x1BD11BDAu;
  x0 += ks0; x1 += ks1;
#define RR(r) { x0 += x1; x1 = (x1 << r) | (x1 >> (32 - r)); x1 ^= x0; }
  RR(13) RR(15) RR(26) RR(6)  x0 += ks1; x1 += ks2 + 1u;
  RR(17) RR(29) RR(16) RR(24) x0 += ks2; x1 += ks0 + 2u;
  RR(13) RR(15) RR(26) RR(6)  x0 += ks0; x1 += ks1 + 3u;
  RR(17) RR(29) RR(16) RR(24) x0 += ks1; x1 += ks2 + 4u;
  RR(13) RR(15) RR(26) RR(6)  x0 += ks2; x1 += ks0 + 5u;
#undef RR
  o0 = x0; o1 = x1;
}

__device__ __forceinline__ float drop_scale(unsigned k0, unsigned k1, unsigned flat) {
#if JAX_PARTITIONABLE
  unsigned o0, o1; tf2x32(k0, k1, 0u, flat, o0, o1);
  unsigned bits = o0 ^ o1;
#else
  unsigned o0, o1, bits;
  if (flat < 8192u) { tf2x32(k0, k1, flat, flat + 8192u, o0, o1); bits = o0; }
  else             { tf2x32(k0, k1, flat - 8192u, flat, o0, o1); bits = o1; }
#endif
  return (bits >> 31) ? 0.0f : 2.0f;
}
__device__ __forceinline__ void get_drop_keys(unsigned &a0, unsigned &a1,
                                              unsigned &b0, unsigned &b1) {
#if JAX_PARTITIONABLE
  tf2x32(0u, 42u, 0u, 0u, a0, a1);
  tf2x32(0u, 42u, 0u, 1u, b0, b1);
#else
  unsigned p0, q0, p1, q1;
  tf2x32(0u, 42u, 0u, 2u, p0, q0);
  tf2x32(0u, 42u, 1u, 3u, p1, q1);
  a0 = p0; a1 = p1; b0 = q0; b1 = q1;
#endif
}

// ---------- device-scope grid barrier ----------
// Safety: grid = 512 blocks x 256 thr, __launch_bounds__(256,2) caps VGPR<=256,
// static LDS 21KB -> >=2 blocks/CU * 256 CU = 512 resident at launch => all
// blocks co-resident, spin cannot deadlock. Counter is monotonic within one
// kernel execution (target = NB*phase); k0 re-zeroes it before every replay
// (workspace is poison-filled between iterations). Bounded spin turns any
// surprise into a numeric failure instead of a hang.
__device__ __forceinline__ void gbar(int* cnt, int target) {
  __syncthreads();
  if (threadIdx.x == 0) {
    __threadfence();
    __hip_atomic_fetch_add(cnt, 1, __ATOMIC_ACQ_REL, __HIP_MEMORY_SCOPE_AGENT);
    long long guard = 0;
    while (__hip_atomic_load(cnt, __ATOMIC_ACQUIRE, __HIP_MEMORY_SCOPE_AGENT) < target) {
      __builtin_amdgcn_s_sleep(2);
      if (++guard > (1LL << 26)) break;
    }
  }
  __syncthreads();
}

// =================================================================
// k0: zero barrier counters (ws is poisoned between iterations)
// =================================================================
__global__ void k0(int* cnt) {
  if (threadIdx.x < 16) cnt[threadIdx.x] = 0;
}

// =================================================================
// kM: whole decoder step, 13 phases / 12 grid barriers
// =================================================================
__global__ __launch_bounds__(256, 2) void kM(
    const float* es, const float* esp, const float* prenet_in,
    const float* rnn1_hidden, const float* rnn2_hidden,
    const float* rnn1_cell, const float* rnn2_cell,
    const float* context_vec, const float* attn_hidden, const int* chars,
    const float* conv_b, const float* L_w, const float* W_w, const float* W_b, const float* v_w,
    const float* fc1_w, const float* fc1_b, const float* fc2_w, const float* fc2_b,
    const float* gru_w_ih, const float* gru_w_hh, const float* gru_b_ih, const float* gru_b_hh,
    const float* ri_w, const float* ri_b,
    const float* l1_w_ih, const float* l1_w_hh, const float* l1_b_ih, const float* l1_b_hh,
    const float* l2_w_ih, const float* l2_w_hh, const float* l2_b_ih, const float* l2_b_hh,
    const float* mp_w, const float* sp_w, const float* sp_b,
    float* ws,
    float* mels_o, float* scores_o, float* attn_o, float* h1_o, float* h2_o,
    float* c1_o, float* c2_o, float* ctx_o, float* stop_o) {
  int* cnt = (int*)ws;
  float* pqc     = ws + 64;        // 128
  float* phT     = ws + 192;       // 16384
  float* poT     = phT + 16384;    // 16384
  float* attn_hT = poT + 16384;    // 8192
  float* giT     = attn_hT + 8192; // 24576
  float* ghT     = giT + 24576;    // 24576
  float* u_buf   = ghT + 24576;    // 65536
  float* partial = u_buf + 65536;  // 262144 (8 tc x 64 b x 512 d)
  float* ctxT    = partial + 262144; // 32768
  float* xT      = ctxT + 32768;   // 32768
  float* x2T     = xT + 32768;     // 32768
  float* x3T     = x2T + 32768;    // 32768
  float* g1T     = x3T + 32768;    // 131072
  float* g2T     = g1T + 131072;   // 131072
  float* h1pT    = g2T + 131072;   // 32768
  float* h2pT    = h1pT + 32768;   // 32768
  float* cvT     = h2pT + 32768;   // 32768
  float* ahT0    = cvT + 32768;    // 8192  (end: 917696 floats = 3.67 MB)

  const int g = blockIdx.x, tid = threadIdx.x;
  const int w = tid >> 6, lane = tid & 63;
  __shared__ float sh[5248];

  // ---------------- phase 1: fc1 + input transposes ----------------
  if (g < 64) {
    // stage prenet_in in LDS (pad 80->81 to kill bank conflicts)
    for (int i = tid; i < 5120; i += 256) sh[(i / 80) * 81 + (i % 80)] = prenet_in[i];
    __syncthreads();
    unsigned d1k0, d1k1, d2k0, d2k1;
    get_drop_keys(d1k0, d1k1, d2k0, d2k1);
    const int j = g * 4 + w;
    float acc = fc1_b[j];
    const float* wr = fc1_w + j * 80;
    #pragma unroll 8
    for (int k = 0; k < 80; k += 2) {
      float2 wv = *(const float2*)(wr + k);
      acc += sh[lane * 81 + k] * wv.x + sh[lane * 81 + k + 1] * wv.y;
    }
    acc = fmaxf(acc, 0.0f) * drop_scale(d1k0, d1k1, (unsigned)(lane * 256 + j));
    phT[j * 64 + lane] = acc;
  } else if (g < 128) {
    int base = (g - 64) * 512;
    #pragma unroll
    for (int e = 0; e < 2; e++) { int i = base + tid + e * 256; h1pT[i] = rnn1_hidden[(i & 63) * 512 + (i >> 6)]; }
  } else if (g < 192) {
    int base = (g - 128) * 512;
    #pragma unroll
    for (int e = 0; e < 2; e++) { int i = base + tid + e * 256; h2pT[i] = rnn2_hidden[(i & 63) * 512 + (i >> 6)]; }
  } else if (g < 256) {
    int base = (g - 192) * 512;
    #pragma unroll
    for (int e = 0; e < 2; e++) { int i = base + tid + e * 256; cvT[i] = context_vec[(i & 63) * 512 + (i >> 6)]; }
  } else if (g < 272) {
    int base = (g - 256) * 512;
    #pragma unroll
    for (int e = 0; e < 2; e++) { int i = base + tid + e * 256; ahT0[i] = attn_hidden[(i & 63) * 128 + (i >> 6)]; }
  }
  gbar(cnt, 1 * NB);

  // ---------------- phase 2: fc2 ----------------
  if (g < 64) {
    unsigned d1k0, d1k1, d2k0, d2k1;
    get_drop_keys(d1k0, d1k1, d2k0, d2k1);
    const int j = g * 4 + w;
    float acc = fc2_b[j];
    const float* wr = fc2_w + j * 256;
    #pragma unroll 8
    for (int k = 0; k < 256; k += 2) {
      float2 wv = *(const float2*)(wr + k);
      acc += phT[k * 64 + lane] * wv.x + phT[(k + 1) * 64 + lane] * wv.y;
    }
    acc = fmaxf(acc, 0.0f) * drop_scale(d2k0, d2k1, (unsigned)(lane * 256 + j));
    poT[j * 64 + lane] = acc;
  }
  gbar(cnt, 2 * NB);

  // ---------------- phase 3: GRU matmuls + pqc ----------------
  if (g < 96) {                    // gi: 384 rows, K=768, whole row per wave
    const int n = g * 4 + w;
    float acc = gru_b_ih[n];
    const float* wr = gru_w_ih + (size_t)n * 768;
    #pragma unroll 4
    for (int k = 0; k < 512; k += 2) {
      float2 wv = *(const float2*)(wr + k);
      acc += cvT[k * 64 + lane] * wv.x + cvT[(k + 1) * 64 + lane] * wv.y;
    }
    #pragma unroll 4
    for (int k = 512; k < 768; k += 2) {
      float2 wv = *(const float2*)(wr + k);
      acc += poT[(k - 512) * 64 + lane] * wv.x + poT[(k - 511) * 64 + lane] * wv.y;
    }
    giT[n * 64 + lane] = acc;
  } else if (g < 192) {            // gh: 384 rows, K=128
    const int n = (g - 96) * 4 + w;
    float acc = gru_b_hh[n];
    const float* wr = gru_w_hh + n * 128;
    #pragma unroll 4
    for (int k = 0; k < 128; k += 2) {
      float2 wv = *(const float2*)(wr + k);
      acc += ahT0[k * 64 + lane] * wv.x + ahT0[(k + 1) * 64 + lane] * wv.y;
    }
    ghT[n * 64 + lane] = acc;
  } else if (g == 192) {           // pqc[n] = W_b[n] + conv_b . L_w[n]
    if (tid < 128) {
      float acc = W_b[tid];
      const float* lw = L_w + tid * 32;
      #pragma unroll
      for (int f = 0; f < 32; f++) acc += conv_b[f] * lw[f];
      pqc[tid] = acc;
    }
  }
  gbar(cnt, 3 * NB);

  // ---------------- phase 4: GRU gates ----------------
  if (g < 32) {
    int i = g * 256 + tid, j = i >> 6, b = i & 63;
    float r = sigm(giT[i] + ghT[i]);
    float z = sigm(giT[8192 + i] + ghT[8192 + i]);
    float nn = tanh_f(giT[16384 + i] + r * ghT[16384 + i]);
    float h = (1.0f - z) * nn + z * ahT0[i];
    attn_o[b * 128 + j] = h;
    attn_hT[i] = h;
  }
  gbar(cnt, 4 * NB);

  // ---------------- phase 5: pq (per-block) + u ----------------
  {
    const int b = g >> 3, tch = g & 7;
    float2 a2 = *(const float2*)(attn_o + b * 128 + 2 * lane);
    for (int ni = 0; ni < 32; ni++) {
      int n = w * 32 + ni;
      float2 wv = *(const float2*)(W_w + n * 128 + 2 * lane);
      float s = a2.x * wv.x + a2.y * wv.y;
      for (int off = 32; off > 0; off >>= 1) s += __shfl_xor(s, off, 64);
      if (lane == 0) sh[n] = s + pqc[n];
    }
    __syncthreads();
    float2 p = *(const float2*)(sh + 2 * lane);
    float2 v2 = *(const float2*)(v_w + 2 * lane);
    const int tb = tch * 128 + w * 32;
    const float* erow = esp + ((size_t)b * 1024 + tb) * 128 + 2 * lane;
    for (int i2 = 0; i2 < 8; i2++) {
      const float* er = erow + (size_t)i2 * 512;
      float2 e0 = *(const float2*)(er);
      float2 e1 = *(const float2*)(er + 128);
      float2 e2 = *(const float2*)(er + 256);
      float2 e3 = *(const float2*)(er + 384);
      float s0 = v2.x * tanh_f(p.x + e0.x) + v2.y * tanh_f(p.y + e0.y);
      float s1 = v2.x * tanh_f(p.x + e1.x) + v2.y * tanh_f(p.y + e1.y);
      float s2 = v2.x * tanh_f(p.x + e2.x) + v2.y * tanh_f(p.y + e2.y);
      float s3 = v2.x * tanh_f(p.x + e3.x) + v2.y * tanh_f(p.y + e3.y);
      for (int off = 32; off > 0; off >>= 1) {
        s0 += __shfl_down(s0, off, 64);
        s1 += __shfl_down(s1, off, 64);
        s2 += __shfl_down(s2, off, 64);
        s3 += __shfl_down(s3, off, 64);
      }
      if (lane == 0) {
        int t = tb + i2 * 4;
        u_buf[b * 1024 + t]     = (chars[b * 1024 + t]     != 0) ? s0 : 0.0f;
        u_buf[b * 1024 + t + 1] = (chars[b * 1024 + t + 1] != 0) ? s1 : 0.0f;
        u_buf[b * 1024 + t + 2] = (chars[b * 1024 + t + 2] != 0) ? s2 : 0.0f;
        u_buf[b * 1024 + t + 3] = (chars[b * 1024 + t + 3] != 0) ? s3 : 0.0f;
      }
    }
  }
  gbar(cnt, 5 * NB);

  // ---------------- phase 6: softmax (per-block) + context partials ----------------
  {
    const int b = g >> 3, tch = g & 7;
    float* redm = sh;          // 256
    float* sc   = sh + 256;    // 128
    float* red4 = sh + 384;    // 2048
    float4 uv = *(const float4*)(u_buf + b * 1024 + tid * 4);
    float m = fmaxf(fmaxf(uv.x, uv.y), fmaxf(uv.z, uv.w));
    redm[tid] = m;
    __syncthreads();
    for (int s = 128; s > 0; s >>= 1) { if (tid < s) redm[tid] = fmaxf(redm[tid], redm[tid + s]); __syncthreads(); }
    float M = redm[0];
    __syncthreads();
    float e0 = __expf(uv.x - M), e1 = __expf(uv.y - M), e2 = __expf(uv.z - M), e3 = __expf(uv.w - M);
    redm[tid] = e0 + e1 + e2 + e3;
    __syncthreads();
    for (int s = 128; s > 0; s >>= 1) { if (tid < s) redm[tid] += redm[tid + s]; __syncthreads(); }
    float inv = 1.0f / redm[0];
    if (tch == 0) {
      float4 r; r.x = e0 * inv; r.y = e1 * inv; r.z = e2 * inv; r.w = e3 * inv;
      *(float4*)(scores_o + b * 1024 + tid * 4) = r;
    }
    if (tid < 128) sc[tid] = __expf(u_buf[b * 1024 + tch * 128 + tid] - M) * inv;
    __syncthreads();
    float acc0 = 0, acc1 = 0, acc2 = 0, acc3 = 0, acc4 = 0, acc5 = 0, acc6 = 0, acc7 = 0;
    const float* base = es + ((size_t)b * 1024 + tch * 128) * 512 + lane * 8;
    for (int i = 0; i < 32; i += 2) {
      int t1 = 4 * i + w, t2 = t1 + 4;
      float4 wa1 = *(const float4*)(base + (size_t)t1 * 512);
      float4 wb1 = *(const float4*)(base + (size_t)t1 * 512 + 4);
      float4 wa2 = *(const float4*)(base + (size_t)t2 * 512);
      float4 wb2 = *(const float4*)(base + (size_t)t2 * 512 + 4);
      float s1 = sc[t1], s2 = sc[t2];
      acc0 += s1 * wa1.x + s2 * wa2.x; acc1 += s1 * wa1.y + s2 * wa2.y;
      acc2 += s1 * wa1.z + s2 * wa2.z; acc3 += s1 * wa1.w + s2 * wa2.w;
      acc4 += s1 * wb1.x + s2 * wb2.x; acc5 += s1 * wb1.y + s2 * wb2.y;
      acc6 += s1 * wb1.z + s2 * wb2.z; acc7 += s1 * wb1.w + s2 * wb2.w;
    }
    float* rr = red4 + w * 512 + lane * 8;
    rr[0] = acc0; rr[1] = acc1; rr[2] = acc2; rr[3] = acc3;
    rr[4] = acc4; rr[5] = acc5; rr[6] = acc6; rr[7] = acc7;
    __syncthreads();
    int d0 = tid * 2;
    float r0 = red4[d0] + red4[512 + d0] + red4[1024 + d0] + red4[1536 + d0];
    float r1 = red4[d0 + 1] + red4[512 + d0 + 1] + red4[1024 + d0 + 1] + red4[1536 + d0 + 1];
    float* pp = partial + ((size_t)tch * 64 + b) * 512 + d0;
    pp[0] = r0; pp[1] = r1;
  }
  gbar(cnt, 6 * NB);

  // ---------------- phase 7: reduce partials -> ctx_o + ctxT ----------------
  if (g < 64) {
    const int b = g, d = tid * 2;
    float v0 = 0, v1 = 0;
    #pragma unroll
    for (int tc = 0; tc < 8; tc++) {
      const float* pp = partial + ((size_t)tc * 64 + b) * 512 + d;
      v0 += pp[0]; v1 += pp[1];
    }
    float2 ov; ov.x = v0; ov.y = v1;
    *(float2*)(ctx_o + b * 512 + d) = ov;
    ctxT[d * 64 + b] = v0;
    ctxT[(d + 1) * 64 + b] = v1;
  }
  gbar(cnt, 7 * NB);

  // ---------------- phase 8: x = concat(ctx, attn_h) @ ri_w.T + ri_b ----------------
  {
    const int n = g;
    const int k0 = w * 160, k1 = k0 + 160;
    const float* wr = ri_w + (size_t)n * 640;
    float acc = 0.0f;
    for (int k = k0; k < k1; k += 2) {
      float x0 = (k < 512) ? ctxT[k * 64 + lane] : attn_hT[(k - 512) * 64 + lane];
      float x1 = (k + 1 < 512) ? ctxT[(k + 1) * 64 + lane] : attn_hT[(k - 511) * 64 + lane];
      float2 wv = *(const float2*)(wr + k);
      acc += x0 * wv.x + x1 * wv.y;
    }
    sh[w * 64 + lane] = acc;
    __syncthreads();
    if (tid < 64) xT[n * 64 + tid] = ri_b[n] + sh[tid] + sh[64 + tid] + sh[128 + tid] + sh[192 + tid];
  }
  gbar(cnt, 8 * NB);

  // ---------------- phase 9: LSTM1 gate matmul (whole rows, no atomics) ----------------
  {
    const int n = g * 4 + w;   // 2048 rows
    float acc = l1_b_ih[n] + l1_b_hh[n];
    const float* wi = l1_w_ih + (size_t)n * 512;
    const float* wh = l1_w_hh + (size_t)n * 512;
    #pragma unroll 4
    for (int k = 0; k < 512; k += 2) {
      float2 wv = *(const float2*)(wi + k);
      acc += xT[k * 64 + lane] * wv.x + xT[(k + 1) * 64 + lane] * wv.y;
    }
    #pragma unroll 4
    for (int k = 0; k < 512; k += 2) {
      float2 wv = *(const float2*)(wh + k);
      acc += h1pT[k * 64 + lane] * wv.x + h1pT[(k + 1) * 64 + lane] * wv.y;
    }
    g1T[n * 64 + lane] = acc;
  }
  gbar(cnt, 9 * NB);

  // ---------------- phase 10: LSTM1 gates ----------------
  if (g < 128) {
    int i = g * 256 + tid, j = i >> 6, b = i & 63;
    float gi = g1T[i], gf = g1T[32768 + i], gg = g1T[65536 + i], go = g1T[98304 + i];
    float c = rnn1_cell[b * 512 + j];
    float c2 = sigm(gf) * c + sigm(gi) * tanh_f(gg);
    float h2v = sigm(go) * tanh_f(c2);
    h1_o[b * 512 + j] = h2v;
    c1_o[b * 512 + j] = c2;
    x2T[i] = xT[i] + h2v;
  }
  gbar(cnt, 10 * NB);

  // ---------------- phase 11: LSTM2 gate matmul ----------------
  {
    const int n = g * 4 + w;
    float acc = l2_b_ih[n] + l2_b_hh[n];
    const float* wi = l2_w_ih + (size_t)n * 512;
    const float* wh = l2_w_hh + (size_t)n * 512;
    #pragma unroll 4
    for (int k = 0; k < 512; k += 2) {
      float2 wv = *(const float2*)(wi + k);
      acc += x2T[k * 64 + lane] * wv.x + x2T[(k + 1) * 64 + lane] * wv.y;
    }
    #pragma unroll 4
    for (int k = 0; k < 512; k += 2) {
      float2 wv = *(const float2*)(wh + k);
      acc += h2pT[k * 64 + lane] * wv.x + h2pT[(k + 1) * 64 + lane] * wv.y;
    }
    g2T[n * 64 + lane] = acc;
  }
  gbar(cnt, 11 * NB);

  // ---------------- phase 12: LSTM2 gates ----------------
  if (g < 128) {
    int i = g * 256 + tid, j = i >> 6, b = i & 63;
    float gi = g2T[i], gf = g2T[32768 + i], gg = g2T[65536 + i], go = g2T[98304 + i];
    float c = rnn2_cell[b * 512 + j];
    float c2 = sigm(gf) * c + sigm(gi) * tanh_f(gg);
    float h2v = sigm(go) * tanh_f(c2);
    h2_o[b * 512 + j] = h2v;
    c2_o[b * 512 + j] = c2;
    x3T[i] = x2T[i] + h2v;
  }
  gbar(cnt, 12 * NB);

  // ---------------- phase 13: mels + stop ----------------
  if (g < 21) {
    int wv = g * 4 + w;
    if (wv < 80) {
      const float* wr = mp_w + (size_t)wv * 20 * 512;
      float acc = 0.0f;
      #pragma unroll 4
      for (int k = 0; k < 512; k += 2) {
        float2 wv2 = *(const float2*)(wr + k);
        acc += x3T[k * 64 + lane] * wv2.x + x3T[(k + 1) * 64 + lane] * wv2.y;
      }
      mels_o[lane * 80 + wv] = acc;
    } else if (wv == 80) {
      float acc = sp_b[0];
      #pragma unroll 4
      for (int k = 0; k < 512; k += 2) {
        float2 wv2 = *(const float2*)(sp_w + k);
        acc += x3T[k * 64 + lane] * wv2.x + x3T[(k + 1) * 64 + lane] * wv2.y;
      }
      #pragma unroll 4
      for (int k = 0; k < 512; k += 2) {
        float2 wv2 = *(const float2*)(sp_w + 512 + k);
        acc += ctxT[k * 64 + lane] * wv2.x + ctxT[(k + 1) * 64 + lane] * wv2.y;
      }
      stop_o[lane] = sigm(acc);
    }
  }
}

// =================================================================
extern "C" void kernel_launch(void* const* d_in, const int* in_sizes, int n_in,
                              void* d_out, int out_size, void* d_ws, size_t ws_size,
                              hipStream_t stream) {
  const float* es          = (const float*)d_in[0];
  const float* esp         = (const float*)d_in[1];
  const float* prenet_in   = (const float*)d_in[2];
  const float* attn_hidden = (const float*)d_in[3];
  const float* rnn1_hidden = (const float*)d_in[4];
  const float* rnn2_hidden = (const float*)d_in[5];
  const float* rnn1_cell   = (const float*)d_in[6];
  const float* rnn2_cell   = (const float*)d_in[7];
  const float* context_vec = (const float*)d_in[8];
  const int* chars         = (const int*)d_in[9];
  // d_in[10] = t (unused), d_in[11] = conv_w (unused: conv input is zeros)
  const float* conv_b = (const float*)d_in[12];
  const float* L_w    = (const float*)d_in[13];
  const float* W_w    = (const float*)d_in[14];
  const float* W_b    = (const float*)d_in[15];
  const float* v_w    = (const float*)d_in[16];
  const float* fc1_w  = (const float*)d_in[17];
  const float* fc1_b  = (const float*)d_in[18];
  const float* fc2_w  = (const float*)d_in[19];
  const float* fc2_b  = (const float*)d_in[20];
  const float* gru_w_ih = (const float*)d_in[21];
  const float* gru_w_hh = (const float*)d_in[22];
  const float* gru_b_ih = (const float*)d_in[23];
  const float* gru_b_hh = (const float*)d_in[24];
  const float* ri_w   = (const float*)d_in[25];
  const float* ri_b   = (const float*)d_in[26];
  const float* l1_w_ih = (const float*)d_in[27];
  const float* l1_w_hh = (const float*)d_in[28];
  const float* l1_b_ih = (const float*)d_in[29];
  const float* l1_b_hh = (const float*)d_in[30];
  const float* l2_w_ih = (const float*)d_in[31];
  const float* l2_w_hh = (const float*)d_in[32];
  const float* l2_b_ih = (const float*)d_in[33];
  const float* l2_b_hh = (const float*)d_in[34];
  const float* mp_w = (const float*)d_in[35];
  const float* sp_w = (const float*)d_in[36];
  const float* sp_b = (const float*)d_in[37];

  float* out = (float*)d_out;
  float* ws = (float*)d_ws;

  float* mels_o   = out + 0;
  float* scores_o = out + 5120;
  float* attn_o   = out + 70656;
  float* h1_o     = out + 78848;
  float* h2_o     = out + 111616;
  float* c1_o     = out + 144384;
  float* c2_o     = out + 177152;
  float* ctx_o    = out + 209920;
  float* stop_o   = out + 242688;

  k0<<<1, 64, 0, stream>>>((int*)ws);
  kM<<<NB, 256, 0, stream>>>(es, esp, prenet_in, rnn1_hidden, rnn2_hidden,
                             rnn1_cell, rnn2_cell, context_vec, attn_hidden, chars,
                             conv_b, L_w, W_w, W_b, v_w,
                             fc1_w, fc1_b, fc2_w, fc2_b,
                             gru_w_ih, gru_w_hh, gru_b_ih, gru_b_hh,
                             ri_w, ri_b,
                             l1_w_ih, l1_w_hh, l1_b_ih, l1_b_hh,
                             l2_w_ih, l2_w_hh, l2_b_ih, l2_b_hh,
                             mp_w, sp_w, sp_b,
                             ws,
                             mels_o, scores_o, attn_o, h1_o, h2_o,
                             c1_o, c2_o, ctx_o, stop_o);
}

// Round 3
// 692.474 us; speedup vs baseline: 1.8454x; 1.8454x over previous
//
#include <hip/hip_runtime.h>
#include <stdint.h>

#define JAX_PARTITIONABLE 1
#define NB 512

// ---------- helpers ----------
__device__ __forceinline__ float tanh_f(float x) {
  float e = __expf(2.0f * x);
  return 1.0f - 2.0f / (e + 1.0f);
}
__device__ __forceinline__ float sigm(float x) {
  return 1.0f / (1.0f + __expf(-x));
}

// ---------- Threefry-2x32 (JAX-compatible) ----------
__device__ __forceinline__ void tf2x32(unsigned k0, unsigned k1, unsigned x0, unsigned x1,
                                       unsigned &o0, unsigned &o1) {
  unsigned ks0 = k0, ks1 = k1, ks2 = k0 ^ k1 ^ 0x1BD11BDAu;
  x0 += ks0; x1 += ks1;
#define RR(r) { x0 += x1; x1 = (x1 << r) | (x1 >> (32 - r)); x1 ^= x0; }
  RR(13) RR(15) RR(26) RR(6)  x0 += ks1; x1 += ks2 + 1u;
  RR(17) RR(29) RR(16) RR(24) x0 += ks2; x1 += ks0 + 2u;
  RR(13) RR(15) RR(26) RR(6)  x0 += ks0; x1 += ks1 + 3u;
  RR(17) RR(29) RR(16) RR(24) x0 += ks1; x1 += ks2 + 4u;
  RR(13) RR(15) RR(26) RR(6)  x0 += ks2; x1 += ks0 + 5u;
#undef RR
  o0 = x0; o1 = x1;
}

__device__ __forceinline__ float drop_scale(unsigned k0, unsigned k1, unsigned flat) {
#if JAX_PARTITIONABLE
  unsigned o0, o1; tf2x32(k0, k1, 0u, flat, o0, o1);
  unsigned bits = o0 ^ o1;
#else
  unsigned o0, o1, bits;
  if (flat < 8192u) { tf2x32(k0, k1, flat, flat + 8192u, o0, o1); bits = o0; }
  else             { tf2x32(k0, k1, flat - 8192u, flat, o0, o1); bits = o1; }
#endif
  return (bits >> 31) ? 0.0f : 2.0f;
}
__device__ __forceinline__ void get_drop_keys(unsigned &a0, unsigned &a1,
                                              unsigned &b0, unsigned &b1) {
#if JAX_PARTITIONABLE
  tf2x32(0u, 42u, 0u, 0u, a0, a1);
  tf2x32(0u, 42u, 0u, 1u, b0, b1);
#else
  unsigned p0, q0, p1, q1;
  tf2x32(0u, 42u, 0u, 2u, p0, q0);
  tf2x32(0u, 42u, 1u, 3u, p1, q1);
  a0 = p0; a1 = p1; b0 = q0; b1 = q1;
#endif
}

// ---------- device-scope grid barrier (low-contention, no poll-invalidate) ----------
// Arrival: one ACQ_REL fetch_add per block on a single counter (release makes this
// block's writes visible agent-wide). Last arriver (sees old == target-1, and its
// acquire RMW synchronizes with all earlier releases) stores the phase number to 16
// distributed flag lines. Waiters poll their line with RELAXED loads (NO L2
// invalidate per poll — the R2 bug) throttled by s_sleep, then execute ONE acquire
// load before proceeding. Counter+flags monotonic within a run; k0 re-zeroes them
// before every replay. Bounded spin => wrong answer instead of hang on surprise.
__device__ __forceinline__ void gbar(int* cnt, int* flags, int phase) {
  __syncthreads();
  if (threadIdx.x == 0) {
    int old = __hip_atomic_fetch_add(cnt, 1, __ATOMIC_ACQ_REL, __HIP_MEMORY_SCOPE_AGENT);
    if (old == phase * NB - 1) {
      #pragma unroll
      for (int i = 0; i < 16; i++)
        __hip_atomic_store(flags + i * 64, phase, __ATOMIC_RELEASE, __HIP_MEMORY_SCOPE_AGENT);
    } else {
      int* myflag = flags + (int)(blockIdx.x & 15) * 64;
      long long guard = 0;
      while (__hip_atomic_load(myflag, __ATOMIC_RELAXED, __HIP_MEMORY_SCOPE_AGENT) < phase) {
        __builtin_amdgcn_s_sleep(8);
        if (++guard > (1LL << 19)) break;
      }
      int f = __hip_atomic_load(myflag, __ATOMIC_ACQUIRE, __HIP_MEMORY_SCOPE_AGENT);
      asm volatile("" :: "v"(f));  // keep the acquire load alive
    }
  }
  __syncthreads();
}

// =================================================================
// k0: zero barrier counter + flags (ws is poisoned between iterations)
// =================================================================
__global__ void k0(int* cnt) {
  for (int i = threadIdx.x; i < 1088; i += 256) cnt[i] = 0;
}

// =================================================================
// kM: whole decoder step, 10 phases / 9 grid barriers
// =================================================================
__global__ __launch_bounds__(256, 2) void kM(
    const float* es, const float* esp, const float* prenet_in,
    const float* rnn1_hidden, const float* rnn2_hidden,
    const float* rnn1_cell, const float* rnn2_cell,
    const float* context_vec, const float* attn_hidden, const int* chars,
    const float* conv_b, const float* L_w, const float* W_w, const float* W_b, const float* v_w,
    const float* fc1_w, const float* fc1_b, const float* fc2_w, const float* fc2_b,
    const float* gru_w_ih, const float* gru_w_hh, const float* gru_b_ih, const float* gru_b_hh,
    const float* ri_w, const float* ri_b,
    const float* l1_w_ih, const float* l1_w_hh, const float* l1_b_ih, const float* l1_b_hh,
    const float* l2_w_ih, const float* l2_w_hh, const float* l2_b_ih, const float* l2_b_hh,
    const float* mp_w, const float* sp_w, const float* sp_b,
    float* ws,
    float* mels_o, float* scores_o, float* attn_o, float* h1_o, float* h2_o,
    float* c1_o, float* c2_o, float* ctx_o, float* stop_o) {
  int* cnt   = (int*)ws;          // [0]
  int* flags = (int*)ws + 64;     // 16 slots x 64 ints
  float* pqc     = ws + 1088;     // 128
  float* phT     = ws + 1216;     // 16384
  float* poT     = phT + 16384;   // 16384
  float* attn_hT = poT + 16384;   // 8192
  float* giT     = attn_hT + 8192;  // 24576
  float* ghT     = giT + 24576;   // 24576
  float* u_buf   = ghT + 24576;   // 65536
  float* ctxT    = u_buf + 65536; // 32768 (atomic-accumulated; zeroed in P1)
  float* xT      = ctxT + 32768;  // 32768
  float* x2T     = xT + 32768;    // 32768
  float* g1T     = x2T + 32768;   // 131072
  float* g2T     = g1T + 131072;  // 131072
  float* h1pT    = g2T + 131072;  // 32768
  float* h2pT    = h1pT + 32768;  // 32768
  float* cvT     = h2pT + 32768;  // 32768
  float* ahT0    = cvT + 32768;   // 8192
  float* c1pT    = ahT0 + 8192;   // 32768
  float* c2pT    = c1pT + 32768;  // 32768 (end: 689344 floats = 2.76 MB)

  const int g = blockIdx.x, tid = threadIdx.x;
  const int w = tid >> 6, lane = tid & 63;
  __shared__ float sh[5248];

  // ---------------- P1: fc1 + input transposes + zero ctxT ----------------
  if (g < 64) {
    for (int i = tid; i < 5120; i += 256) sh[(i / 80) * 81 + (i % 80)] = prenet_in[i];
    __syncthreads();
    unsigned d1k0, d1k1, d2k0, d2k1;
    get_drop_keys(d1k0, d1k1, d2k0, d2k1);
    const int j = g * 4 + w;
    float acc = fc1_b[j];
    const float* wr = fc1_w + j * 80;
    #pragma unroll 8
    for (int k = 0; k < 80; k += 2) {
      float2 wv = *(const float2*)(wr + k);
      acc += sh[lane * 81 + k] * wv.x + sh[lane * 81 + k + 1] * wv.y;
    }
    acc = fmaxf(acc, 0.0f) * drop_scale(d1k0, d1k1, (unsigned)(lane * 256 + j));
    phT[j * 64 + lane] = acc;
  } else if (g < 128) {
    int base = (g - 64) * 512;
    #pragma unroll
    for (int e = 0; e < 2; e++) { int i = base + tid + e * 256; h1pT[i] = rnn1_hidden[(i & 63) * 512 + (i >> 6)]; }
  } else if (g < 192) {
    int base = (g - 128) * 512;
    #pragma unroll
    for (int e = 0; e < 2; e++) { int i = base + tid + e * 256; h2pT[i] = rnn2_hidden[(i & 63) * 512 + (i >> 6)]; }
  } else if (g < 256) {
    int base = (g - 192) * 512;
    #pragma unroll
    for (int e = 0; e < 2; e++) { int i = base + tid + e * 256; cvT[i] = context_vec[(i & 63) * 512 + (i >> 6)]; }
  } else if (g < 272) {
    int base = (g - 256) * 512;
    #pragma unroll
    for (int e = 0; e < 2; e++) { int i = base + tid + e * 256; ahT0[i] = attn_hidden[(i & 63) * 128 + (i >> 6)]; }
  } else if (g < 336) {
    int base = (g - 272) * 512;
    #pragma unroll
    for (int e = 0; e < 2; e++) { int i = base + tid + e * 256; c1pT[i] = rnn1_cell[(i & 63) * 512 + (i >> 6)]; }
  } else if (g < 400) {
    int base = (g - 336) * 512;
    #pragma unroll
    for (int e = 0; e < 2; e++) { int i = base + tid + e * 256; c2pT[i] = rnn2_cell[(i & 63) * 512 + (i >> 6)]; }
  } else if (g < 464) {
    int base = (g - 400) * 512;
    #pragma unroll
    for (int e = 0; e < 2; e++) ctxT[base + tid + e * 256] = 0.0f;
  }
  gbar(cnt, flags, 1);

  // ---------------- P2: fc2 ----------------
  if (g < 64) {
    unsigned d1k0, d1k1, d2k0, d2k1;
    get_drop_keys(d1k0, d1k1, d2k0, d2k1);
    const int j = g * 4 + w;
    float acc = fc2_b[j];
    const float* wr = fc2_w + j * 256;
    #pragma unroll 8
    for (int k = 0; k < 256; k += 2) {
      float2 wv = *(const float2*)(wr + k);
      acc += phT[k * 64 + lane] * wv.x + phT[(k + 1) * 64 + lane] * wv.y;
    }
    acc = fmaxf(acc, 0.0f) * drop_scale(d2k0, d2k1, (unsigned)(lane * 256 + j));
    poT[j * 64 + lane] = acc;
  }
  gbar(cnt, flags, 2);

  // ---------------- P3: GRU matmuls + pqc ----------------
  if (g < 96) {                    // gi: 384 rows, K=768
    const int n = g * 4 + w;
    float acc = gru_b_ih[n];
    const float* wr = gru_w_ih + (size_t)n * 768;
    #pragma unroll 4
    for (int k = 0; k < 512; k += 2) {
      float2 wv = *(const float2*)(wr + k);
      acc += cvT[k * 64 + lane] * wv.x + cvT[(k + 1) * 64 + lane] * wv.y;
    }
    #pragma unroll 4
    for (int k = 512; k < 768; k += 2) {
      float2 wv = *(const float2*)(wr + k);
      acc += poT[(k - 512) * 64 + lane] * wv.x + poT[(k - 511) * 64 + lane] * wv.y;
    }
    giT[n * 64 + lane] = acc;
  } else if (g < 192) {            // gh: 384 rows, K=128
    const int n = (g - 96) * 4 + w;
    float acc = gru_b_hh[n];
    const float* wr = gru_w_hh + n * 128;
    #pragma unroll 4
    for (int k = 0; k < 128; k += 2) {
      float2 wv = *(const float2*)(wr + k);
      acc += ahT0[k * 64 + lane] * wv.x + ahT0[(k + 1) * 64 + lane] * wv.y;
    }
    ghT[n * 64 + lane] = acc;
  } else if (g == 192) {           // pqc[n] = W_b[n] + conv_b . L_w[n]
    if (tid < 128) {
      float acc = W_b[tid];
      const float* lw = L_w + tid * 32;
      #pragma unroll
      for (int f = 0; f < 32; f++) acc += conv_b[f] * lw[f];
      pqc[tid] = acc;
    }
  }
  gbar(cnt, flags, 3);

  // ---------------- P4: GRU gates (per-block recompute) + pq + u ----------------
  {
    const int b = g >> 3, tch = g & 7;
    float* pqs = sh;         // 128
    float* shh = sh + 128;   // 128
    if (tid < 128) {
      float gr = giT[tid * 64 + b] + ghT[tid * 64 + b];
      float gz = giT[(128 + tid) * 64 + b] + ghT[(128 + tid) * 64 + b];
      float gni = giT[(256 + tid) * 64 + b];
      float gnh = ghT[(256 + tid) * 64 + b];
      float a0 = ahT0[tid * 64 + b];
      float r = sigm(gr), z = sigm(gz);
      float h = (1.0f - z) * tanh_f(gni + r * gnh) + z * a0;
      shh[tid] = h;
      if (tch == 0) { attn_o[b * 128 + tid] = h; attn_hT[tid * 64 + b] = h; }
    }
    __syncthreads();
    float2 a2; a2.x = shh[2 * lane]; a2.y = shh[2 * lane + 1];
    for (int ni = 0; ni < 32; ni++) {
      int n = w * 32 + ni;
      float2 wv2 = *(const float2*)(W_w + n * 128 + 2 * lane);
      float s = a2.x * wv2.x + a2.y * wv2.y;
      for (int off = 32; off > 0; off >>= 1) s += __shfl_xor(s, off, 64);
      if (lane == 0) pqs[n] = s + pqc[n];
    }
    __syncthreads();
    float2 p = *(const float2*)(pqs + 2 * lane);
    float2 v2 = *(const float2*)(v_w + 2 * lane);
    const int tb = tch * 128 + w * 32;
    const float* erow = esp + ((size_t)b * 1024 + tb) * 128 + 2 * lane;
    for (int i2 = 0; i2 < 8; i2++) {
      const float* er = erow + (size_t)i2 * 512;
      float2 e0 = *(const float2*)(er);
      float2 e1 = *(const float2*)(er + 128);
      float2 e2 = *(const float2*)(er + 256);
      float2 e3 = *(const float2*)(er + 384);
      float s0 = v2.x * tanh_f(p.x + e0.x) + v2.y * tanh_f(p.y + e0.y);
      float s1 = v2.x * tanh_f(p.x + e1.x) + v2.y * tanh_f(p.y + e1.y);
      float s2 = v2.x * tanh_f(p.x + e2.x) + v2.y * tanh_f(p.y + e2.y);
      float s3 = v2.x * tanh_f(p.x + e3.x) + v2.y * tanh_f(p.y + e3.y);
      for (int off = 32; off > 0; off >>= 1) {
        s0 += __shfl_down(s0, off, 64);
        s1 += __shfl_down(s1, off, 64);
        s2 += __shfl_down(s2, off, 64);
        s3 += __shfl_down(s3, off, 64);
      }
      if (lane == 0) {
        int t = tb + i2 * 4;
        u_buf[b * 1024 + t]     = (chars[b * 1024 + t]     != 0) ? s0 : 0.0f;
        u_buf[b * 1024 + t + 1] = (chars[b * 1024 + t + 1] != 0) ? s1 : 0.0f;
        u_buf[b * 1024 + t + 2] = (chars[b * 1024 + t + 2] != 0) ? s2 : 0.0f;
        u_buf[b * 1024 + t + 3] = (chars[b * 1024 + t + 3] != 0) ? s3 : 0.0f;
      }
    }
  }
  gbar(cnt, flags, 4);

  // ---------------- P5: softmax (per-block) + context atomicAdd into ctxT ----------------
  {
    const int b = g >> 3, tch = g & 7;
    float* redm = sh;          // 256
    float* sc   = sh + 256;    // 128
    float* red4 = sh + 384;    // 2048
    float4 uv = *(const float4*)(u_buf + b * 1024 + tid * 4);
    float m = fmaxf(fmaxf(uv.x, uv.y), fmaxf(uv.z, uv.w));
    redm[tid] = m;
    __syncthreads();
    for (int s = 128; s > 0; s >>= 1) { if (tid < s) redm[tid] = fmaxf(redm[tid], redm[tid + s]); __syncthreads(); }
    float M = redm[0];
    __syncthreads();
    float e0 = __expf(uv.x - M), e1 = __expf(uv.y - M), e2 = __expf(uv.z - M), e3 = __expf(uv.w - M);
    redm[tid] = e0 + e1 + e2 + e3;
    __syncthreads();
    for (int s = 128; s > 0; s >>= 1) { if (tid < s) redm[tid] += redm[tid + s]; __syncthreads(); }
    float inv = 1.0f / redm[0];
    if (tch == 0) {
      float4 r; r.x = e0 * inv; r.y = e1 * inv; r.z = e2 * inv; r.w = e3 * inv;
      *(float4*)(scores_o + b * 1024 + tid * 4) = r;
    }
    if (tid < 128) sc[tid] = __expf(u_buf[b * 1024 + tch * 128 + tid] - M) * inv;
    __syncthreads();
    float acc0 = 0, acc1 = 0, acc2 = 0, acc3 = 0, acc4 = 0, acc5 = 0, acc6 = 0, acc7 = 0;
    const float* base = es + ((size_t)b * 1024 + tch * 128) * 512 + lane * 8;
    for (int i = 0; i < 32; i += 2) {
      int t1 = 4 * i + w, t2 = t1 + 4;
      float4 wa1 = *(const float4*)(base + (size_t)t1 * 512);
      float4 wb1 = *(const float4*)(base + (size_t)t1 * 512 + 4);
      float4 wa2 = *(const float4*)(base + (size_t)t2 * 512);
      float4 wb2 = *(const float4*)(base + (size_t)t2 * 512 + 4);
      float s1 = sc[t1], s2 = sc[t2];
      acc0 += s1 * wa1.x + s2 * wa2.x; acc1 += s1 * wa1.y + s2 * wa2.y;
      acc2 += s1 * wa1.z + s2 * wa2.z; acc3 += s1 * wa1.w + s2 * wa2.w;
      acc4 += s1 * wb1.x + s2 * wb2.x; acc5 += s1 * wb1.y + s2 * wb2.y;
      acc6 += s1 * wb1.z + s2 * wb2.z; acc7 += s1 * wb1.w + s2 * wb2.w;
    }
    float* rr = red4 + w * 512 + lane * 8;
    rr[0] = acc0; rr[1] = acc1; rr[2] = acc2; rr[3] = acc3;
    rr[4] = acc4; rr[5] = acc5; rr[6] = acc6; rr[7] = acc7;
    __syncthreads();
    int d0 = tid * 2;
    float r0 = red4[d0] + red4[512 + d0] + red4[1024 + d0] + red4[1536 + d0];
    float r1 = red4[d0 + 1] + red4[512 + d0 + 1] + red4[1024 + d0 + 1] + red4[1536 + d0 + 1];
    atomicAdd(&ctxT[d0 * 64 + b], r0);
    atomicAdd(&ctxT[(d0 + 1) * 64 + b], r1);
  }
  gbar(cnt, flags, 5);

  // ---------------- P6: xT = concat(ctx, attn_h) @ ri_w.T + ri_b ; ctx_o ----------------
  {
    const int n = g;
    if (tid < 64) ctx_o[tid * 512 + n] = ctxT[n * 64 + tid];
    const int k0 = w * 160, k1 = k0 + 160;
    const float* wr = ri_w + (size_t)n * 640;
    float acc = 0.0f;
    for (int k = k0; k < k1; k += 2) {
      float x0 = (k < 512) ? ctxT[k * 64 + lane] : attn_hT[(k - 512) * 64 + lane];
      float x1 = (k + 1 < 512) ? ctxT[(k + 1) * 64 + lane] : attn_hT[(k - 511) * 64 + lane];
      float2 wv2 = *(const float2*)(wr + k);
      acc += x0 * wv2.x + x1 * wv2.y;
    }
    sh[w * 64 + lane] = acc;
    __syncthreads();
    if (tid < 64) xT[n * 64 + tid] = ri_b[n] + sh[tid] + sh[64 + tid] + sh[128 + tid] + sh[192 + tid];
  }
  gbar(cnt, flags, 6);

  // ---------------- P7: LSTM1 gate matmul ----------------
  {
    const int n = g * 4 + w;   // 2048 rows
    float acc = l1_b_ih[n] + l1_b_hh[n];
    const float* wi = l1_w_ih + (size_t)n * 512;
    const float* wh = l1_w_hh + (size_t)n * 512;
    #pragma unroll 4
    for (int k = 0; k < 512; k += 2) {
      float2 wv2 = *(const float2*)(wi + k);
      acc += xT[k * 64 + lane] * wv2.x + xT[(k + 1) * 64 + lane] * wv2.y;
    }
    #pragma unroll 4
    for (int k = 0; k < 512; k += 2) {
      float2 wv2 = *(const float2*)(wh + k);
      acc += h1pT[k * 64 + lane] * wv2.x + h1pT[(k + 1) * 64 + lane] * wv2.y;
    }
    g1T[n * 64 + lane] = acc;
  }
  gbar(cnt, flags, 7);

  // ---------------- P8: LSTM1 gates ----------------
  if (g < 128) {
    int i = g * 256 + tid, j = i >> 6, b = i & 63;
    float gi = g1T[i], gf = g1T[32768 + i], gg = g1T[65536 + i], go = g1T[98304 + i];
    float c = c1pT[i];
    float c2 = sigm(gf) * c + sigm(gi) * tanh_f(gg);
    float h2v = sigm(go) * tanh_f(c2);
    h1_o[b * 512 + j] = h2v;
    c1_o[b * 512 + j] = c2;
    x2T[i] = xT[i] + h2v;
  }
  gbar(cnt, flags, 8);

  // ---------------- P9: LSTM2 gate matmul ----------------
  {
    const int n = g * 4 + w;
    float acc = l2_b_ih[n] + l2_b_hh[n];
    const float* wi = l2_w_ih + (size_t)n * 512;
    const float* wh = l2_w_hh + (size_t)n * 512;
    #pragma unroll 4
    for (int k = 0; k < 512; k += 2) {
      float2 wv2 = *(const float2*)(wi + k);
      acc += x2T[k * 64 + lane] * wv2.x + x2T[(k + 1) * 64 + lane] * wv2.y;
    }
    #pragma unroll 4
    for (int k = 0; k < 512; k += 2) {
      float2 wv2 = *(const float2*)(wh + k);
      acc += h2pT[k * 64 + lane] * wv2.x + h2pT[(k + 1) * 64 + lane] * wv2.y;
    }
    g2T[n * 64 + lane] = acc;
  }
  gbar(cnt, flags, 9);

  // ---------------- P10: LSTM2 gates outputs + mels/stop (inline x3) ----------------
  if (g < 20) {
    // mels rows m = g*4 + j ; wave w covers k-quarter; x3 recomputed inline
    const float* w0 = mp_w + (size_t)(g * 4 + 0) * 20 * 512;
    const float* w1 = mp_w + (size_t)(g * 4 + 1) * 20 * 512;
    const float* w2 = mp_w + (size_t)(g * 4 + 2) * 20 * 512;
    const float* w3 = mp_w + (size_t)(g * 4 + 3) * 20 * 512;
    float acc0 = 0, acc1 = 0, acc2 = 0, acc3 = 0;
    for (int kk = 0; kk < 128; kk++) {
      int k = w * 128 + kk, i = k * 64 + lane;
      float gi = g2T[i], gf = g2T[32768 + i], gg = g2T[65536 + i], go = g2T[98304 + i];
      float c2v = sigm(gf) * c2pT[i] + sigm(gi) * tanh_f(gg);
      float x3 = x2T[i] + sigm(go) * tanh_f(c2v);
      acc0 += x3 * w0[k]; acc1 += x3 * w1[k]; acc2 += x3 * w2[k]; acc3 += x3 * w3[k];
    }
    sh[w * 256 + 0 * 64 + lane] = acc0;
    sh[w * 256 + 1 * 64 + lane] = acc1;
    sh[w * 256 + 2 * 64 + lane] = acc2;
    sh[w * 256 + 3 * 64 + lane] = acc3;
    __syncthreads();
    int j = tid >> 6, ln = tid & 63;
    float s = sh[j * 64 + ln] + sh[256 + j * 64 + ln] + sh[512 + j * 64 + ln] + sh[768 + j * 64 + ln];
    mels_o[ln * 80 + g * 4 + j] = s;
  } else if (g == 20) {
    float acc = 0;
    for (int kk = 0; kk < 128; kk++) {
      int k = w * 128 + kk, i = k * 64 + lane;
      float gi = g2T[i], gf = g2T[32768 + i], gg = g2T[65536 + i], go = g2T[98304 + i];
      float c2v = sigm(gf) * c2pT[i] + sigm(gi) * tanh_f(gg);
      float x3 = x2T[i] + sigm(go) * tanh_f(c2v);
      acc += x3 * sp_w[k] + ctxT[i] * sp_w[512 + k];
    }
    sh[w * 64 + lane] = acc;
    __syncthreads();
    if (tid < 64) stop_o[tid] = sigm(sp_b[0] + sh[tid] + sh[64 + tid] + sh[128 + tid] + sh[192 + tid]);
  } else if (g >= 64 && g < 192) {
    int i = (g - 64) * 256 + tid, j = i >> 6, b = i & 63;
    float gi = g2T[i], gf = g2T[32768 + i], gg = g2T[65536 + i], go = g2T[98304 + i];
    float c2v = sigm(gf) * c2pT[i] + sigm(gi) * tanh_f(gg);
    float h2v = sigm(go) * tanh_f(c2v);
    h2_o[b * 512 + j] = h2v;
    c2_o[b * 512 + j] = c2v;
  }
}

// =================================================================
extern "C" void kernel_launch(void* const* d_in, const int* in_sizes, int n_in,
                              void* d_out, int out_size, void* d_ws, size_t ws_size,
                              hipStream_t stream) {
  const float* es          = (const float*)d_in[0];
  const float* esp         = (const float*)d_in[1];
  const float* prenet_in   = (const float*)d_in[2];
  const float* attn_hidden = (const float*)d_in[3];
  const float* rnn1_hidden = (const float*)d_in[4];
  const float* rnn2_hidden = (const float*)d_in[5];
  const float* rnn1_cell   = (const float*)d_in[6];
  const float* rnn2_cell   = (const float*)d_in[7];
  const float* context_vec = (const float*)d_in[8];
  const int* chars         = (const int*)d_in[9];
  // d_in[10] = t (unused), d_in[11] = conv_w (unused: conv input is zeros)
  const float* conv_b = (const float*)d_in[12];
  const float* L_w    = (const float*)d_in[13];
  const float* W_w    = (const float*)d_in[14];
  const float* W_b    = (const float*)d_in[15];
  const float* v_w    = (const float*)d_in[16];
  const float* fc1_w  = (const float*)d_in[17];
  const float* fc1_b  = (const float*)d_in[18];
  const float* fc2_w  = (const float*)d_in[19];
  const float* fc2_b  = (const float*)d_in[20];
  const float* gru_w_ih = (const float*)d_in[21];
  const float* gru_w_hh = (const float*)d_in[22];
  const float* gru_b_ih = (const float*)d_in[23];
  const float* gru_b_hh = (const float*)d_in[24];
  const float* ri_w   = (const float*)d_in[25];
  const float* ri_b   = (const float*)d_in[26];
  const float* l1_w_ih = (const float*)d_in[27];
  const float* l1_w_hh = (const float*)d_in[28];
  const float* l1_b_ih = (const float*)d_in[29];
  const float* l1_b_hh = (const float*)d_in[30];
  const float* l2_w_ih = (const float*)d_in[31];
  const float* l2_w_hh = (const float*)d_in[32];
  const float* l2_b_ih = (const float*)d_in[33];
  const float* l2_b_hh = (const float*)d_in[34];
  const float* mp_w = (const float*)d_in[35];
  const float* sp_w = (const float*)d_in[36];
  const float* sp_b = (const float*)d_in[37];

  float* out = (float*)d_out;
  float* ws = (float*)d_ws;

  float* mels_o   = out + 0;
  float* scores_o = out + 5120;
  float* attn_o   = out + 70656;
  float* h1_o     = out + 78848;
  float* h2_o     = out + 111616;
  float* c1_o     = out + 144384;
  float* c2_o     = out + 177152;
  float* ctx_o    = out + 209920;
  float* stop_o   = out + 242688;

  k0<<<1, 256, 0, stream>>>((int*)ws);
  kM<<<NB, 256, 0, stream>>>(es, esp, prenet_in, rnn1_hidden, rnn2_hidden,
                             rnn1_cell, rnn2_cell, context_vec, attn_hidden, chars,
                             conv_b, L_w, W_w, W_b, v_w,
                             fc1_w, fc1_b, fc2_w, fc2_b,
                             gru_w_ih, gru_w_hh, gru_b_ih, gru_b_hh,
                             ri_w, ri_b,
                             l1_w_ih, l1_w_hh, l1_b_ih, l1_b_hh,
                             l2_w_ih, l2_w_hh, l2_b_ih, l2_b_hh,
                             mp_w, sp_w, sp_b,
                             ws,
                             mels_o, scores_o, attn_o, h1_o, h2_o,
                             c1_o, c2_o, ctx_o, stop_o);
}

// Round 4
// 548.754 us; speedup vs baseline: 2.3287x; 1.2619x over previous
//
#include <hip/hip_runtime.h>
#include <stdint.h>

#define JAX_PARTITIONABLE 1
#define NB 512

// ---------- helpers ----------
__device__ __forceinline__ float tanh_f(float x) {
  float e = __expf(2.0f * x);
  return 1.0f - 2.0f / (e + 1.0f);
}
__device__ __forceinline__ float sigm(float x) {
  return 1.0f / (1.0f + __expf(-x));
}

// Workspace store: agent-scope relaxed atomic store -> compiles to a plain
// global_store with the device-coherent cache policy (sc1). The store bypasses /
// writes through the producer XCD's private L2 to the coherent memory side (L3),
// so consumers on other XCDs can read it with PLAIN loads after the barrier and
// NO release/acquire cache maintenance is needed anywhere. Correctness relies on
// write-once-then-read dataflow per buffer (verified for every ws buffer below):
// a consumer's L1/L2 can only hold a line it first touched AFTER the producing
// phase's barrier, hence always fresh.
__device__ __forceinline__ void stw(float* p, float v) {
  __hip_atomic_store(p, v, __ATOMIC_RELAXED, __HIP_MEMORY_SCOPE_AGENT);
}

// ---------- Threefry-2x32 (JAX-compatible) ----------
__device__ __forceinline__ void tf2x32(unsigned k0, unsigned k1, unsigned x0, unsigned x1,
                                       unsigned &o0, unsigned &o1) {
  unsigned ks0 = k0, ks1 = k1, ks2 = k0 ^ k1 ^ 0x1BD11BDAu;
  x0 += ks0; x1 += ks1;
#define RR(r) { x0 += x1; x1 = (x1 << r) | (x1 >> (32 - r)); x1 ^= x0; }
  RR(13) RR(15) RR(26) RR(6)  x0 += ks1; x1 += ks2 + 1u;
  RR(17) RR(29) RR(16) RR(24) x0 += ks2; x1 += ks0 + 2u;
  RR(13) RR(15) RR(26) RR(6)  x0 += ks0; x1 += ks1 + 3u;
  RR(17) RR(29) RR(16) RR(24) x0 += ks1; x1 += ks2 + 4u;
  RR(13) RR(15) RR(26) RR(6)  x0 += ks2; x1 += ks0 + 5u;
#undef RR
  o0 = x0; o1 = x1;
}

__device__ __forceinline__ float drop_scale(unsigned k0, unsigned k1, unsigned flat) {
#if JAX_PARTITIONABLE
  unsigned o0, o1; tf2x32(k0, k1, 0u, flat, o0, o1);
  unsigned bits = o0 ^ o1;
#else
  unsigned o0, o1, bits;
  if (flat < 8192u) { tf2x32(k0, k1, flat, flat + 8192u, o0, o1); bits = o0; }
  else             { tf2x32(k0, k1, flat - 8192u, flat, o0, o1); bits = o1; }
#endif
  return (bits >> 31) ? 0.0f : 2.0f;
}
__device__ __forceinline__ void get_drop_keys(unsigned &a0, unsigned &a1,
                                              unsigned &b0, unsigned &b1) {
#if JAX_PARTITIONABLE
  tf2x32(0u, 42u, 0u, 0u, a0, a1);
  tf2x32(0u, 42u, 0u, 1u, b0, b1);
#else
  unsigned p0, q0, p1, q1;
  tf2x32(0u, 42u, 0u, 2u, p0, q0);
  tf2x32(0u, 42u, 1u, 3u, p1, q1);
  a0 = p0; a1 = p1; b0 = q0; b1 = q1;
#endif
}

// ---------- fence-free device barrier ----------
// All atomics RELAXED agent scope (memory-side coherent, NO L2 writeback/invalidate
// — the R2/R3 stall was ~1000 full-L2 maintenance ops per barrier). Data visibility
// is handled by stw() sc1 stores, not by this barrier. Arrival ordering: each
// block's __syncthreads() drains vmcnt before thread0's increment, so all its sc1
// stores are at L3 when the arrival is visible. Two-level counter tree (16x32 then
// 16) avoids same-line serialization of 512 RMWs. Counters/flags monotonic within
// one run; k0 re-zeroes before each replay. Bounded spin -> numeric failure, not hang.
__device__ __forceinline__ void gbar(int* ibase, int phase) {
  __syncthreads();
  if (threadIdx.x == 0) {
    const int s = (int)(blockIdx.x & 15);
    int* sub   = ibase + s * 64;
    int* top   = ibase + 1024;
    int* flags = ibase + 1088;
    int old = __hip_atomic_fetch_add(sub, 1, __ATOMIC_RELAXED, __HIP_MEMORY_SCOPE_AGENT);
    if (old == phase * 32 - 1) {
      int t = __hip_atomic_fetch_add(top, 1, __ATOMIC_RELAXED, __HIP_MEMORY_SCOPE_AGENT);
      if (t == phase * 16 - 1) {
        #pragma unroll
        for (int i = 0; i < 16; i++)
          __hip_atomic_store(flags + i * 64, phase, __ATOMIC_RELAXED, __HIP_MEMORY_SCOPE_AGENT);
      }
    }
    long long guard = 0;
    while (__hip_atomic_load(flags + s * 64, __ATOMIC_RELAXED, __HIP_MEMORY_SCOPE_AGENT) < phase) {
      __builtin_amdgcn_s_sleep(4);
      if (++guard > (1LL << 21)) break;
    }
  }
  __syncthreads();
}

// =================================================================
// k0: zero barrier counters + flags (ws is poisoned between iterations)
// =================================================================
__global__ void k0(int* cnt) {
  for (int i = threadIdx.x; i < 2112; i += 256) cnt[i] = 0;
}

// =================================================================
// kM: whole decoder step, 10 phases / 9 grid barriers
// =================================================================
__global__ __launch_bounds__(256, 2) void kM(
    const float* es, const float* esp, const float* prenet_in,
    const float* rnn1_hidden, const float* rnn2_hidden,
    const float* rnn1_cell, const float* rnn2_cell,
    const float* context_vec, const float* attn_hidden, const int* chars,
    const float* conv_b, const float* L_w, const float* W_w, const float* W_b, const float* v_w,
    const float* fc1_w, const float* fc1_b, const float* fc2_w, const float* fc2_b,
    const float* gru_w_ih, const float* gru_w_hh, const float* gru_b_ih, const float* gru_b_hh,
    const float* ri_w, const float* ri_b,
    const float* l1_w_ih, const float* l1_w_hh, const float* l1_b_ih, const float* l1_b_hh,
    const float* l2_w_ih, const float* l2_w_hh, const float* l2_b_ih, const float* l2_b_hh,
    const float* mp_w, const float* sp_w, const float* sp_b,
    float* ws,
    float* mels_o, float* scores_o, float* attn_o, float* h1_o, float* h2_o,
    float* c1_o, float* c2_o, float* ctx_o, float* stop_o) {
  int* ibase = (int*)ws;          // 2112 ints: 16x64 sub + 64 top + 16x64 flags
  float* pqc     = ws + 2112;     // 128
  float* phT     = pqc + 128;     // 16384
  float* poT     = phT + 16384;   // 16384
  float* attn_hT = poT + 16384;   // 8192
  float* giT     = attn_hT + 8192;  // 24576
  float* ghT     = giT + 24576;   // 24576
  float* u_buf   = ghT + 24576;   // 65536
  float* ctxT    = u_buf + 65536; // 32768 (atomic-accumulated; zeroed in P1)
  float* xT      = ctxT + 32768;  // 32768
  float* x2T     = xT + 32768;    // 32768
  float* g1T     = x2T + 32768;   // 131072
  float* g2T     = g1T + 131072;  // 131072
  float* h1pT    = g2T + 131072;  // 32768
  float* h2pT    = h1pT + 32768;  // 32768
  float* cvT     = h2pT + 32768;  // 32768
  float* ahT0    = cvT + 32768;   // 8192
  float* c1pT    = ahT0 + 8192;   // 32768
  float* c2pT    = c1pT + 32768;  // 32768

  const int g = blockIdx.x, tid = threadIdx.x;
  const int w = tid >> 6, lane = tid & 63;
  __shared__ float sh[5248];

  // ---------------- P1: fc1 + input transposes + zero ctxT ----------------
  if (g < 64) {
    for (int i = tid; i < 5120; i += 256) sh[(i / 80) * 81 + (i % 80)] = prenet_in[i];
    __syncthreads();
    unsigned d1k0, d1k1, d2k0, d2k1;
    get_drop_keys(d1k0, d1k1, d2k0, d2k1);
    const int j = g * 4 + w;
    float acc = fc1_b[j];
    const float* wr = fc1_w + j * 80;
    #pragma unroll 8
    for (int k = 0; k < 80; k += 2) {
      float2 wv = *(const float2*)(wr + k);
      acc += sh[lane * 81 + k] * wv.x + sh[lane * 81 + k + 1] * wv.y;
    }
    acc = fmaxf(acc, 0.0f) * drop_scale(d1k0, d1k1, (unsigned)(lane * 256 + j));
    stw(&phT[j * 64 + lane], acc);
  } else if (g < 128) {
    int base = (g - 64) * 512;
    #pragma unroll
    for (int e = 0; e < 2; e++) { int i = base + tid + e * 256; stw(&h1pT[i], rnn1_hidden[(i & 63) * 512 + (i >> 6)]); }
  } else if (g < 192) {
    int base = (g - 128) * 512;
    #pragma unroll
    for (int e = 0; e < 2; e++) { int i = base + tid + e * 256; stw(&h2pT[i], rnn2_hidden[(i & 63) * 512 + (i >> 6)]); }
  } else if (g < 256) {
    int base = (g - 192) * 512;
    #pragma unroll
    for (int e = 0; e < 2; e++) { int i = base + tid + e * 256; stw(&cvT[i], context_vec[(i & 63) * 512 + (i >> 6)]); }
  } else if (g < 272) {
    int base = (g - 256) * 512;
    #pragma unroll
    for (int e = 0; e < 2; e++) { int i = base + tid + e * 256; stw(&ahT0[i], attn_hidden[(i & 63) * 128 + (i >> 6)]); }
  } else if (g < 336) {
    int base = (g - 272) * 512;
    #pragma unroll
    for (int e = 0; e < 2; e++) { int i = base + tid + e * 256; stw(&c1pT[i], rnn1_cell[(i & 63) * 512 + (i >> 6)]); }
  } else if (g < 400) {
    int base = (g - 336) * 512;
    #pragma unroll
    for (int e = 0; e < 2; e++) { int i = base + tid + e * 256; stw(&c2pT[i], rnn2_cell[(i & 63) * 512 + (i >> 6)]); }
  } else if (g < 464) {
    int base = (g - 400) * 512;
    #pragma unroll
    for (int e = 0; e < 2; e++) stw(&ctxT[base + tid + e * 256], 0.0f);
  }
  gbar(ibase, 1);

  // ---------------- P2: fc2 ----------------
  if (g < 64) {
    unsigned d1k0, d1k1, d2k0, d2k1;
    get_drop_keys(d1k0, d1k1, d2k0, d2k1);
    const int j = g * 4 + w;
    float acc = fc2_b[j];
    const float* wr = fc2_w + j * 256;
    #pragma unroll 8
    for (int k = 0; k < 256; k += 2) {
      float2 wv = *(const float2*)(wr + k);
      acc += phT[k * 64 + lane] * wv.x + phT[(k + 1) * 64 + lane] * wv.y;
    }
    acc = fmaxf(acc, 0.0f) * drop_scale(d2k0, d2k1, (unsigned)(lane * 256 + j));
    stw(&poT[j * 64 + lane], acc);
  }
  gbar(ibase, 2);

  // ---------------- P3: GRU matmuls + pqc ----------------
  if (g < 96) {                    // gi: 384 rows, K=768
    const int n = g * 4 + w;
    float acc = gru_b_ih[n];
    const float* wr = gru_w_ih + (size_t)n * 768;
    #pragma unroll 4
    for (int k = 0; k < 512; k += 2) {
      float2 wv = *(const float2*)(wr + k);
      acc += cvT[k * 64 + lane] * wv.x + cvT[(k + 1) * 64 + lane] * wv.y;
    }
    #pragma unroll 4
    for (int k = 512; k < 768; k += 2) {
      float2 wv = *(const float2*)(wr + k);
      acc += poT[(k - 512) * 64 + lane] * wv.x + poT[(k - 511) * 64 + lane] * wv.y;
    }
    stw(&giT[n * 64 + lane], acc);
  } else if (g < 192) {            // gh: 384 rows, K=128
    const int n = (g - 96) * 4 + w;
    float acc = gru_b_hh[n];
    const float* wr = gru_w_hh + n * 128;
    #pragma unroll 4
    for (int k = 0; k < 128; k += 2) {
      float2 wv = *(const float2*)(wr + k);
      acc += ahT0[k * 64 + lane] * wv.x + ahT0[(k + 1) * 64 + lane] * wv.y;
    }
    stw(&ghT[n * 64 + lane], acc);
  } else if (g == 192) {           // pqc[n] = W_b[n] + conv_b . L_w[n]
    if (tid < 128) {
      float acc = W_b[tid];
      const float* lw = L_w + tid * 32;
      #pragma unroll
      for (int f = 0; f < 32; f++) acc += conv_b[f] * lw[f];
      stw(&pqc[tid], acc);
    }
  }
  gbar(ibase, 3);

  // ---------------- P4: GRU gates (per-block recompute) + pq + u ----------------
  {
    const int b = g >> 3, tch = g & 7;
    float* pqs = sh;         // 128
    float* shh = sh + 128;   // 128
    if (tid < 128) {
      float gr = giT[tid * 64 + b] + ghT[tid * 64 + b];
      float gz = giT[(128 + tid) * 64 + b] + ghT[(128 + tid) * 64 + b];
      float gni = giT[(256 + tid) * 64 + b];
      float gnh = ghT[(256 + tid) * 64 + b];
      float a0 = ahT0[tid * 64 + b];
      float r = sigm(gr), z = sigm(gz);
      float h = (1.0f - z) * tanh_f(gni + r * gnh) + z * a0;
      shh[tid] = h;
      if (tch == 0) { attn_o[b * 128 + tid] = h; stw(&attn_hT[tid * 64 + b], h); }
    }
    __syncthreads();
    float2 a2; a2.x = shh[2 * lane]; a2.y = shh[2 * lane + 1];
    for (int ni = 0; ni < 32; ni++) {
      int n = w * 32 + ni;
      float2 wv2 = *(const float2*)(W_w + n * 128 + 2 * lane);
      float s = a2.x * wv2.x + a2.y * wv2.y;
      for (int off = 32; off > 0; off >>= 1) s += __shfl_xor(s, off, 64);
      if (lane == 0) pqs[n] = s + pqc[n];
    }
    __syncthreads();
    float2 p = *(const float2*)(pqs + 2 * lane);
    float2 v2 = *(const float2*)(v_w + 2 * lane);
    const int tb = tch * 128 + w * 32;
    const float* erow = esp + ((size_t)b * 1024 + tb) * 128 + 2 * lane;
    for (int i2 = 0; i2 < 8; i2++) {
      const float* er = erow + (size_t)i2 * 512;
      float2 e0 = *(const float2*)(er);
      float2 e1 = *(const float2*)(er + 128);
      float2 e2 = *(const float2*)(er + 256);
      float2 e3 = *(const float2*)(er + 384);
      float s0 = v2.x * tanh_f(p.x + e0.x) + v2.y * tanh_f(p.y + e0.y);
      float s1 = v2.x * tanh_f(p.x + e1.x) + v2.y * tanh_f(p.y + e1.y);
      float s2 = v2.x * tanh_f(p.x + e2.x) + v2.y * tanh_f(p.y + e2.y);
      float s3 = v2.x * tanh_f(p.x + e3.x) + v2.y * tanh_f(p.y + e3.y);
      for (int off = 32; off > 0; off >>= 1) {
        s0 += __shfl_down(s0, off, 64);
        s1 += __shfl_down(s1, off, 64);
        s2 += __shfl_down(s2, off, 64);
        s3 += __shfl_down(s3, off, 64);
      }
      if (lane == 0) {
        int t = tb + i2 * 4;
        stw(&u_buf[b * 1024 + t],     (chars[b * 1024 + t]     != 0) ? s0 : 0.0f);
        stw(&u_buf[b * 1024 + t + 1], (chars[b * 1024 + t + 1] != 0) ? s1 : 0.0f);
        stw(&u_buf[b * 1024 + t + 2], (chars[b * 1024 + t + 2] != 0) ? s2 : 0.0f);
        stw(&u_buf[b * 1024 + t + 3], (chars[b * 1024 + t + 3] != 0) ? s3 : 0.0f);
      }
    }
  }
  gbar(ibase, 4);

  // ---------------- P5: softmax (per-block) + context atomicAdd into ctxT ----------------
  {
    const int b = g >> 3, tch = g & 7;
    float* redm = sh;          // 256
    float* sc   = sh + 256;    // 128
    float* red4 = sh + 384;    // 2048
    float4 uv = *(const float4*)(u_buf + b * 1024 + tid * 4);
    float m = fmaxf(fmaxf(uv.x, uv.y), fmaxf(uv.z, uv.w));
    redm[tid] = m;
    __syncthreads();
    for (int s = 128; s > 0; s >>= 1) { if (tid < s) redm[tid] = fmaxf(redm[tid], redm[tid + s]); __syncthreads(); }
    float M = redm[0];
    __syncthreads();
    float e0 = __expf(uv.x - M), e1 = __expf(uv.y - M), e2 = __expf(uv.z - M), e3 = __expf(uv.w - M);
    redm[tid] = e0 + e1 + e2 + e3;
    __syncthreads();
    for (int s = 128; s > 0; s >>= 1) { if (tid < s) redm[tid] += redm[tid + s]; __syncthreads(); }
    float inv = 1.0f / redm[0];
    if (tch == 0) {
      float4 r; r.x = e0 * inv; r.y = e1 * inv; r.z = e2 * inv; r.w = e3 * inv;
      *(float4*)(scores_o + b * 1024 + tid * 4) = r;
    }
    if (tid < 128) sc[tid] = __expf(u_buf[b * 1024 + tch * 128 + tid] - M) * inv;
    __syncthreads();
    float acc0 = 0, acc1 = 0, acc2 = 0, acc3 = 0, acc4 = 0, acc5 = 0, acc6 = 0, acc7 = 0;
    const float* base = es + ((size_t)b * 1024 + tch * 128) * 512 + lane * 8;
    for (int i = 0; i < 32; i += 2) {
      int t1 = 4 * i + w, t2 = t1 + 4;
      float4 wa1 = *(const float4*)(base + (size_t)t1 * 512);
      float4 wb1 = *(const float4*)(base + (size_t)t1 * 512 + 4);
      float4 wa2 = *(const float4*)(base + (size_t)t2 * 512);
      float4 wb2 = *(const float4*)(base + (size_t)t2 * 512 + 4);
      float s1 = sc[t1], s2 = sc[t2];
      acc0 += s1 * wa1.x + s2 * wa2.x; acc1 += s1 * wa1.y + s2 * wa2.y;
      acc2 += s1 * wa1.z + s2 * wa2.z; acc3 += s1 * wa1.w + s2 * wa2.w;
      acc4 += s1 * wb1.x + s2 * wb2.x; acc5 += s1 * wb1.y + s2 * wb2.y;
      acc6 += s1 * wb1.z + s2 * wb2.z; acc7 += s1 * wb1.w + s2 * wb2.w;
    }
    float* rr = red4 + w * 512 + lane * 8;
    rr[0] = acc0; rr[1] = acc1; rr[2] = acc2; rr[3] = acc3;
    rr[4] = acc4; rr[5] = acc5; rr[6] = acc6; rr[7] = acc7;
    __syncthreads();
    int d0 = tid * 2;
    float r0 = red4[d0] + red4[512 + d0] + red4[1024 + d0] + red4[1536 + d0];
    float r1 = red4[d0 + 1] + red4[512 + d0 + 1] + red4[1024 + d0 + 1] + red4[1536 + d0 + 1];
    atomicAdd(&ctxT[d0 * 64 + b], r0);
    atomicAdd(&ctxT[(d0 + 1) * 64 + b], r1);
  }
  gbar(ibase, 5);

  // ---------------- P6: xT = concat(ctx, attn_h) @ ri_w.T + ri_b ; ctx_o ----------------
  {
    const int n = g;
    if (tid < 64) ctx_o[tid * 512 + n] = ctxT[n * 64 + tid];
    const int k0 = w * 160, k1 = k0 + 160;
    const float* wr = ri_w + (size_t)n * 640;
    float acc = 0.0f;
    for (int k = k0; k < k1; k += 2) {
      float x0 = (k < 512) ? ctxT[k * 64 + lane] : attn_hT[(k - 512) * 64 + lane];
      float x1 = (k + 1 < 512) ? ctxT[(k + 1) * 64 + lane] : attn_hT[(k - 511) * 64 + lane];
      float2 wv2 = *(const float2*)(wr + k);
      acc += x0 * wv2.x + x1 * wv2.y;
    }
    sh[w * 64 + lane] = acc;
    __syncthreads();
    if (tid < 64) stw(&xT[n * 64 + tid], ri_b[n] + sh[tid] + sh[64 + tid] + sh[128 + tid] + sh[192 + tid]);
  }
  gbar(ibase, 6);

  // ---------------- P7: LSTM1 gate matmul ----------------
  {
    const int n = g * 4 + w;   // 2048 rows
    float acc = l1_b_ih[n] + l1_b_hh[n];
    const float* wi = l1_w_ih + (size_t)n * 512;
    const float* wh = l1_w_hh + (size_t)n * 512;
    #pragma unroll 4
    for (int k = 0; k < 512; k += 2) {
      float2 wv2 = *(const float2*)(wi + k);
      acc += xT[k * 64 + lane] * wv2.x + xT[(k + 1) * 64 + lane] * wv2.y;
    }
    #pragma unroll 4
    for (int k = 0; k < 512; k += 2) {
      float2 wv2 = *(const float2*)(wh + k);
      acc += h1pT[k * 64 + lane] * wv2.x + h1pT[(k + 1) * 64 + lane] * wv2.y;
    }
    stw(&g1T[n * 64 + lane], acc);
  }
  gbar(ibase, 7);

  // ---------------- P8: LSTM1 gates ----------------
  if (g < 128) {
    int i = g * 256 + tid, j = i >> 6, b = i & 63;
    float gi = g1T[i], gf = g1T[32768 + i], gg = g1T[65536 + i], go = g1T[98304 + i];
    float c = c1pT[i];
    float c2 = sigm(gf) * c + sigm(gi) * tanh_f(gg);
    float h2v = sigm(go) * tanh_f(c2);
    h1_o[b * 512 + j] = h2v;
    c1_o[b * 512 + j] = c2;
    stw(&x2T[i], xT[i] + h2v);
  }
  gbar(ibase, 8);

  // ---------------- P9: LSTM2 gate matmul ----------------
  {
    const int n = g * 4 + w;
    float acc = l2_b_ih[n] + l2_b_hh[n];
    const float* wi = l2_w_ih + (size_t)n * 512;
    const float* wh = l2_w_hh + (size_t)n * 512;
    #pragma unroll 4
    for (int k = 0; k < 512; k += 2) {
      float2 wv2 = *(const float2*)(wi + k);
      acc += x2T[k * 64 + lane] * wv2.x + x2T[(k + 1) * 64 + lane] * wv2.y;
    }
    #pragma unroll 4
    for (int k = 0; k < 512; k += 2) {
      float2 wv2 = *(const float2*)(wh + k);
      acc += h2pT[k * 64 + lane] * wv2.x + h2pT[(k + 1) * 64 + lane] * wv2.y;
    }
    stw(&g2T[n * 64 + lane], acc);
  }
  gbar(ibase, 9);

  // ---------------- P10: LSTM2 gates outputs + mels/stop (inline x3) ----------------
  if (g < 20) {
    const float* w0 = mp_w + (size_t)(g * 4 + 0) * 20 * 512;
    const float* w1 = mp_w + (size_t)(g * 4 + 1) * 20 * 512;
    const float* w2 = mp_w + (size_t)(g * 4 + 2) * 20 * 512;
    const float* w3 = mp_w + (size_t)(g * 4 + 3) * 20 * 512;
    float acc0 = 0, acc1 = 0, acc2 = 0, acc3 = 0;
    for (int kk = 0; kk < 128; kk++) {
      int k = w * 128 + kk, i = k * 64 + lane;
      float gi = g2T[i], gf = g2T[32768 + i], gg = g2T[65536 + i], go = g2T[98304 + i];
      float c2v = sigm(gf) * c2pT[i] + sigm(gi) * tanh_f(gg);
      float x3 = x2T[i] + sigm(go) * tanh_f(c2v);
      acc0 += x3 * w0[k]; acc1 += x3 * w1[k]; acc2 += x3 * w2[k]; acc3 += x3 * w3[k];
    }
    sh[w * 256 + 0 * 64 + lane] = acc0;
    sh[w * 256 + 1 * 64 + lane] = acc1;
    sh[w * 256 + 2 * 64 + lane] = acc2;
    sh[w * 256 + 3 * 64 + lane] = acc3;
    __syncthreads();
    int j = tid >> 6, ln = tid & 63;
    float s = sh[j * 64 + ln] + sh[256 + j * 64 + ln] + sh[512 + j * 64 + ln] + sh[768 + j * 64 + ln];
    mels_o[ln * 80 + g * 4 + j] = s;
  } else if (g == 20) {
    float acc = 0;
    for (int kk = 0; kk < 128; kk++) {
      int k = w * 128 + kk, i = k * 64 + lane;
      float gi = g2T[i], gf = g2T[32768 + i], gg = g2T[65536 + i], go = g2T[98304 + i];
      float c2v = sigm(gf) * c2pT[i] + sigm(gi) * tanh_f(gg);
      float x3 = x2T[i] + sigm(go) * tanh_f(c2v);
      acc += x3 * sp_w[k] + ctxT[i] * sp_w[512 + k];
    }
    sh[w * 64 + lane] = acc;
    __syncthreads();
    if (tid < 64) stop_o[tid] = sigm(sp_b[0] + sh[tid] + sh[64 + tid] + sh[128 + tid] + sh[192 + tid]);
  } else if (g >= 64 && g < 192) {
    int i = (g - 64) * 256 + tid, j = i >> 6, b = i & 63;
    float gi = g2T[i], gf = g2T[32768 + i], gg = g2T[65536 + i], go = g2T[98304 + i];
    float c2v = sigm(gf) * c2pT[i] + sigm(gi) * tanh_f(gg);
    float h2v = sigm(go) * tanh_f(c2v);
    h2_o[b * 512 + j] = h2v;
    c2_o[b * 512 + j] = c2v;
  }
}

// =================================================================
extern "C" void kernel_launch(void* const* d_in, const int* in_sizes, int n_in,
                              void* d_out, int out_size, void* d_ws, size_t ws_size,
                              hipStream_t stream) {
  const float* es          = (const float*)d_in[0];
  const float* esp         = (const float*)d_in[1];
  const float* prenet_in   = (const float*)d_in[2];
  const float* attn_hidden = (const float*)d_in[3];
  const float* rnn1_hidden = (const float*)d_in[4];
  const float* rnn2_hidden = (const float*)d_in[5];
  const float* rnn1_cell   = (const float*)d_in[6];
  const float* rnn2_cell   = (const float*)d_in[7];
  const float* context_vec = (const float*)d_in[8];
  const int* chars         = (const int*)d_in[9];
  // d_in[10] = t (unused), d_in[11] = conv_w (unused: conv input is zeros)
  const float* conv_b = (const float*)d_in[12];
  const float* L_w    = (const float*)d_in[13];
  const float* W_w    = (const float*)d_in[14];
  const float* W_b    = (const float*)d_in[15];
  const float* v_w    = (const float*)d_in[16];
  const float* fc1_w  = (const float*)d_in[17];
  const float* fc1_b  = (const float*)d_in[18];
  const float* fc2_w  = (const float*)d_in[19];
  const float* fc2_b  = (const float*)d_in[20];
  const float* gru_w_ih = (const float*)d_in[21];
  const float* gru_w_hh = (const float*)d_in[22];
  const float* gru_b_ih = (const float*)d_in[23];
  const float* gru_b_hh = (const float*)d_in[24];
  const float* ri_w   = (const float*)d_in[25];
  const float* ri_b   = (const float*)d_in[26];
  const float* l1_w_ih = (const float*)d_in[27];
  const float* l1_w_hh = (const float*)d_in[28];
  const float* l1_b_ih = (const float*)d_in[29];
  const float* l1_b_hh = (const float*)d_in[30];
  const float* l2_w_ih = (const float*)d_in[31];
  const float* l2_w_hh = (const float*)d_in[32];
  const float* l2_b_ih = (const float*)d_in[33];
  const float* l2_b_hh = (const float*)d_in[34];
  const float* mp_w = (const float*)d_in[35];
  const float* sp_w = (const float*)d_in[36];
  const float* sp_b = (const float*)d_in[37];

  float* out = (float*)d_out;
  float* ws = (float*)d_ws;

  float* mels_o   = out + 0;
  float* scores_o = out + 5120;
  float* attn_o   = out + 70656;
  float* h1_o     = out + 78848;
  float* h2_o     = out + 111616;
  float* c1_o     = out + 144384;
  float* c2_o     = out + 177152;
  float* ctx_o    = out + 209920;
  float* stop_o   = out + 242688;

  k0<<<1, 256, 0, stream>>>((int*)ws);
  kM<<<NB, 256, 0, stream>>>(es, esp, prenet_in, rnn1_hidden, rnn2_hidden,
                             rnn1_cell, rnn2_cell, context_vec, attn_hidden, chars,
                             conv_b, L_w, W_w, W_b, v_w,
                             fc1_w, fc1_b, fc2_w, fc2_b,
                             gru_w_ih, gru_w_hh, gru_b_ih, gru_b_hh,
                             ri_w, ri_b,
                             l1_w_ih, l1_w_hh, l1_b_ih, l1_b_hh,
                             l2_w_ih, l2_w_hh, l2_b_ih, l2_b_hh,
                             mp_w, sp_w, sp_b,
                             ws,
                             mels_o, scores_o, attn_o, h1_o, h2_o,
                             c1_o, c2_o, ctx_o, stop_o);
}

// Round 5
// 487.288 us; speedup vs baseline: 2.6224x; 1.1261x over previous
//
#include <hip/hip_runtime.h>
#include <stdint.h>

#define JAX_PARTITIONABLE 1
#define NB 512

// ---------- helpers ----------
__device__ __forceinline__ float tanh_f(float x) {
  float e = __expf(2.0f * x);
  return 1.0f - 2.0f / (e + 1.0f);
}
__device__ __forceinline__ float sigm(float x) {
  return 1.0f / (1.0f + __expf(-x));
}

// Workspace store: agent-scope relaxed atomic store (sc1 write-through to the
// coherent memory side). Consumers use PLAIN loads after the barrier; their
// first touch of the line is always post-barrier (write-once-then-read dataflow
// per buffer), hence always fresh. No release/acquire cache maintenance anywhere.
__device__ __forceinline__ void stw(float* p, float v) {
  __hip_atomic_store(p, v, __ATOMIC_RELAXED, __HIP_MEMORY_SCOPE_AGENT);
}

// ---------- Threefry-2x32 (JAX-compatible) ----------
__device__ __forceinline__ void tf2x32(unsigned k0, unsigned k1, unsigned x0, unsigned x1,
                                       unsigned &o0, unsigned &o1) {
  unsigned ks0 = k0, ks1 = k1, ks2 = k0 ^ k1 ^ 0x1BD11BDAu;
  x0 += ks0; x1 += ks1;
#define RR(r) { x0 += x1; x1 = (x1 << r) | (x1 >> (32 - r)); x1 ^= x0; }
  RR(13) RR(15) RR(26) RR(6)  x0 += ks1; x1 += ks2 + 1u;
  RR(17) RR(29) RR(16) RR(24) x0 += ks2; x1 += ks0 + 2u;
  RR(13) RR(15) RR(26) RR(6)  x0 += ks0; x1 += ks1 + 3u;
  RR(17) RR(29) RR(16) RR(24) x0 += ks1; x1 += ks2 + 4u;
  RR(13) RR(15) RR(26) RR(6)  x0 += ks2; x1 += ks0 + 5u;
#undef RR
  o0 = x0; o1 = x1;
}

__device__ __forceinline__ float drop_scale(unsigned k0, unsigned k1, unsigned flat) {
#if JAX_PARTITIONABLE
  unsigned o0, o1; tf2x32(k0, k1, 0u, flat, o0, o1);
  unsigned bits = o0 ^ o1;
#else
  unsigned o0, o1, bits;
  if (flat < 8192u) { tf2x32(k0, k1, flat, flat + 8192u, o0, o1); bits = o0; }
  else             { tf2x32(k0, k1, flat - 8192u, flat, o0, o1); bits = o1; }
#endif
  return (bits >> 31) ? 0.0f : 2.0f;
}
__device__ __forceinline__ void get_drop_keys(unsigned &a0, unsigned &a1,
                                              unsigned &b0, unsigned &b1) {
#if JAX_PARTITIONABLE
  tf2x32(0u, 42u, 0u, 0u, a0, a1);
  tf2x32(0u, 42u, 0u, 1u, b0, b1);
#else
  unsigned p0, q0, p1, q1;
  tf2x32(0u, 42u, 0u, 2u, p0, q0);
  tf2x32(0u, 42u, 1u, 3u, p1, q1);
  a0 = p0; a1 = p1; b0 = q0; b1 = q1;
#endif
}

// ---------- fence-free device barrier (R4 design, unchanged) ----------
__device__ __forceinline__ void gbar(int* ibase, int phase) {
  __syncthreads();
  if (threadIdx.x == 0) {
    const int s = (int)(blockIdx.x & 15);
    int* sub   = ibase + s * 64;
    int* top   = ibase + 1024;
    int* flags = ibase + 1088;
    int old = __hip_atomic_fetch_add(sub, 1, __ATOMIC_RELAXED, __HIP_MEMORY_SCOPE_AGENT);
    if (old == phase * 32 - 1) {
      int t = __hip_atomic_fetch_add(top, 1, __ATOMIC_RELAXED, __HIP_MEMORY_SCOPE_AGENT);
      if (t == phase * 16 - 1) {
        #pragma unroll
        for (int i = 0; i < 16; i++)
          __hip_atomic_store(flags + i * 64, phase, __ATOMIC_RELAXED, __HIP_MEMORY_SCOPE_AGENT);
      }
    }
    long long guard = 0;
    while (__hip_atomic_load(flags + s * 64, __ATOMIC_RELAXED, __HIP_MEMORY_SCOPE_AGENT) < phase) {
      __builtin_amdgcn_s_sleep(4);
      if (++guard > (1LL << 21)) break;
    }
  }
  __syncthreads();
}

// =================================================================
// k0: zero barrier counters + flags (ws is poisoned between iterations)
// =================================================================
__global__ void k0(int* cnt) {
  for (int i = threadIdx.x; i < 2112; i += 256) cnt[i] = 0;
}

// =================================================================
// kM: whole decoder step, 9 phases / 8 grid barriers
// =================================================================
__global__ __launch_bounds__(256, 2) void kM(
    const float* es, const float* esp, const float* prenet_in,
    const float* rnn1_hidden, const float* rnn2_hidden,
    const float* rnn1_cell, const float* rnn2_cell,
    const float* context_vec, const float* attn_hidden, const int* chars,
    const float* conv_b, const float* L_w, const float* W_w, const float* W_b, const float* v_w,
    const float* fc1_w, const float* fc1_b, const float* fc2_w, const float* fc2_b,
    const float* gru_w_ih, const float* gru_w_hh, const float* gru_b_ih, const float* gru_b_hh,
    const float* ri_w, const float* ri_b,
    const float* l1_w_ih, const float* l1_w_hh, const float* l1_b_ih, const float* l1_b_hh,
    const float* l2_w_ih, const float* l2_w_hh, const float* l2_b_ih, const float* l2_b_hh,
    const float* mp_w, const float* sp_w, const float* sp_b,
    float* ws,
    float* mels_o, float* scores_o, float* attn_o, float* h1_o, float* h2_o,
    float* c1_o, float* c2_o, float* ctx_o, float* stop_o) {
  int* ibase = (int*)ws;            // 2112 ints
  float* pqc     = ws + 2112;       // 128
  float* phT     = pqc + 128;       // 16384
  float* poT     = phT + 16384;     // 16384
  float* attn_hT = poT + 16384;     // 8192
  float* u_buf   = attn_hT + 8192;  // 65536
  float* ctxT    = u_buf + 65536;   // 32768 (atomic-accumulated; zeroed in P1)
  float* xT      = ctxT + 32768;    // 32768
  float* x2T     = xT + 32768;      // 32768
  float* x3T     = x2T + 32768;     // 32768
  float* h1pT    = x3T + 32768;     // 32768
  float* h2pT    = h1pT + 32768;    // 32768
  float* cvT     = h2pT + 32768;    // 32768
  float* ahT0    = cvT + 32768;     // 8192
  float* c1pT    = ahT0 + 8192;     // 32768
  float* c2pT    = c1pT + 32768;    // 32768

  const int g = blockIdx.x, tid = threadIdx.x;
  const int w = tid >> 6, lane = tid & 63;
  __shared__ float sh[16640];       // 66.5 KB -> 2 blocks/CU (160KB LDS)

  // ---------------- P1: fc1 + input transposes + zero ctxT + pqc ----------------
  if (g < 64) {
    for (int i = tid; i < 5120; i += 256) sh[(i / 80) * 81 + (i % 80)] = prenet_in[i];
    __syncthreads();
    unsigned d1k0, d1k1, d2k0, d2k1;
    get_drop_keys(d1k0, d1k1, d2k0, d2k1);
    const int j = g * 4 + w;
    float acc = fc1_b[j];
    const float* wr = fc1_w + j * 80;
    #pragma unroll 8
    for (int k = 0; k < 80; k += 2) {
      float2 wv = *(const float2*)(wr + k);
      acc += sh[lane * 81 + k] * wv.x + sh[lane * 81 + k + 1] * wv.y;
    }
    acc = fmaxf(acc, 0.0f) * drop_scale(d1k0, d1k1, (unsigned)(lane * 256 + j));
    stw(&phT[j * 64 + lane], acc);
  } else if (g < 128) {
    int base = (g - 64) * 512;
    #pragma unroll
    for (int e = 0; e < 2; e++) { int i = base + tid + e * 256; stw(&h1pT[i], rnn1_hidden[(i & 63) * 512 + (i >> 6)]); }
  } else if (g < 192) {
    int base = (g - 128) * 512;
    #pragma unroll
    for (int e = 0; e < 2; e++) { int i = base + tid + e * 256; stw(&h2pT[i], rnn2_hidden[(i & 63) * 512 + (i >> 6)]); }
  } else if (g < 256) {
    int base = (g - 192) * 512;
    #pragma unroll
    for (int e = 0; e < 2; e++) { int i = base + tid + e * 256; stw(&cvT[i], context_vec[(i & 63) * 512 + (i >> 6)]); }
  } else if (g < 272) {
    int base = (g - 256) * 512;
    #pragma unroll
    for (int e = 0; e < 2; e++) { int i = base + tid + e * 256; stw(&ahT0[i], attn_hidden[(i & 63) * 128 + (i >> 6)]); }
  } else if (g < 336) {
    int base = (g - 272) * 512;
    #pragma unroll
    for (int e = 0; e < 2; e++) { int i = base + tid + e * 256; stw(&c1pT[i], rnn1_cell[(i & 63) * 512 + (i >> 6)]); }
  } else if (g < 400) {
    int base = (g - 336) * 512;
    #pragma unroll
    for (int e = 0; e < 2; e++) { int i = base + tid + e * 256; stw(&c2pT[i], rnn2_cell[(i & 63) * 512 + (i >> 6)]); }
  } else if (g < 464) {
    int base = (g - 400) * 512;
    #pragma unroll
    for (int e = 0; e < 2; e++) stw(&ctxT[base + tid + e * 256], 0.0f);
  } else if (g == 464) {
    if (tid < 128) {
      float acc = W_b[tid];
      const float* lw = L_w + tid * 32;
      #pragma unroll
      for (int f = 0; f < 32; f++) acc += conv_b[f] * lw[f];
      stw(&pqc[tid], acc);
    }
  }
  gbar(ibase, 1);

  // ---------------- P2: fc2 (LDS-staged weights) | idle blocks warm es into L3 ----------------
  if (g < 64) {
    const int j = g * 4 + w;
    ((float4*)(sh + w * 256))[lane] = ((const float4*)(fc2_w + j * 256))[lane];
    __syncthreads();
    unsigned d1k0, d1k1, d2k0, d2k1;
    get_drop_keys(d1k0, d1k1, d2k0, d2k1);
    float acc = fc2_b[j];
    #pragma unroll 8
    for (int k = 0; k < 256; k += 2) {
      float2 wv = *(const float2*)(sh + w * 256 + k);
      acc += phT[k * 64 + lane] * wv.x + phT[(k + 1) * 64 + lane] * wv.y;
    }
    acc = fmaxf(acc, 0.0f) * drop_scale(d2k0, d2k1, (unsigned)(lane * 256 + j));
    stw(&poT[j * 64 + lane], acc);
  } else {
    // warm es (128 MB = 1048576 lines of 128B): one float per line
    const unsigned wi0 = (unsigned)((g - 64) * 256 + tid);  // 0..114687
    float acc = 0.0f;
    #pragma unroll
    for (int s = 0; s < 10; s++) {
      unsigned idx = wi0 + (unsigned)s * 114688u;
      if (idx < 1048576u) acc += es[(size_t)idx * 32];
    }
    asm volatile("" :: "v"(acc));
  }
  gbar(ibase, 2);

  // ---------------- P3: GRU mm + gates fused (blocks 0-127) | warm esp/W_w/chars ----------------
  if (g < 128) {
    // wave 0..2: gi row (g + 128*w), K=768 ; wave 3: gh rows {g, 128+g, 256+g}, K=128
    if (w < 3) {
      const int rj = g + 128 * w;
      const float4* src = (const float4*)(gru_w_ih + (size_t)rj * 768);
      float4* dst = (float4*)(sh + w * 768);
      #pragma unroll
      for (int q = 0; q < 3; q++) dst[q * 64 + lane] = src[q * 64 + lane];
    } else {
      float4* dst = (float4*)(sh + 2304);
      if (lane < 32) {
        dst[lane]      = ((const float4*)(gru_w_hh + (size_t)g * 128))[lane];
        dst[32 + lane] = ((const float4*)(gru_w_hh + (size_t)(128 + g) * 128))[lane];
        dst[64 + lane] = ((const float4*)(gru_w_hh + (size_t)(256 + g) * 128))[lane];
      }
    }
    __syncthreads();
    if (w < 3) {
      const int rj = g + 128 * w;
      float acc = gru_b_ih[rj];
      #pragma unroll 4
      for (int k = 0; k < 512; k += 2) {
        float2 wv = *(const float2*)(sh + w * 768 + k);
        acc += cvT[k * 64 + lane] * wv.x + cvT[(k + 1) * 64 + lane] * wv.y;
      }
      #pragma unroll 4
      for (int k = 512; k < 768; k += 2) {
        float2 wv = *(const float2*)(sh + w * 768 + k);
        acc += poT[(k - 512) * 64 + lane] * wv.x + poT[(k - 511) * 64 + lane] * wv.y;
      }
      sh[2688 + w * 64 + lane] = acc;
    } else {
      #pragma unroll
      for (int r = 0; r < 3; r++) {
        float acc = gru_b_hh[r * 128 + g];
        #pragma unroll 4
        for (int k = 0; k < 128; k += 2) {
          float2 wv = *(const float2*)(sh + 2304 + r * 128 + k);
          acc += ahT0[k * 64 + lane] * wv.x + ahT0[(k + 1) * 64 + lane] * wv.y;
        }
        sh[2688 + (3 + r) * 64 + lane] = acc;
      }
    }
    __syncthreads();
    if (tid < 64) {
      float gr = sh[2688 + tid]       + sh[2688 + 192 + tid];
      float gz = sh[2688 + 64 + tid]  + sh[2688 + 256 + tid];
      float gin = sh[2688 + 128 + tid];
      float ghn = sh[2688 + 320 + tid];
      float a0 = ahT0[g * 64 + tid];
      float r = sigm(gr), z = sigm(gz);
      float h = (1.0f - z) * tanh_f(gin + r * ghn) + z * a0;
      stw(&attn_hT[g * 64 + tid], h);
      attn_o[tid * 128 + g] = h;
    }
  } else {
    // warm esp (32 MB = 262144 lines) + W_w (512 lines) + chars (2048 lines)
    const unsigned wi0 = (unsigned)((g - 128) * 256 + tid);  // 0..98303
    float acc = 0.0f;
    #pragma unroll
    for (int s = 0; s < 3; s++) {
      unsigned idx = wi0 + (unsigned)s * 98304u;
      if (idx < 262144u) acc += esp[(size_t)idx * 32];
    }
    if (g == 128) { if (tid < 512) acc += W_w[tid * 32]; }
    if (g == 129) {
      #pragma unroll
      for (int s = 0; s < 8; s++) acc += (float)chars[(tid + s * 256) * 32];
    }
    asm volatile("" :: "v"(acc));
  }
  gbar(ibase, 3);

  // ---------------- P4: pq (LDS-staged W_w) + u ----------------
  {
    const int b = g >> 3, tch = g & 7;
    // stage W_w rows [w*32, w*32+32): 4096 floats per wave
    {
      const float4* src = (const float4*)(W_w + (size_t)(w * 32) * 128);
      float4* dst = (float4*)(sh + w * 4096);
      #pragma unroll
      for (int q = 0; q < 16; q++) dst[q * 64 + lane] = src[q * 64 + lane];
    }
    float* pqs = sh + 16384;   // 128
    float* shh = sh + 16512;   // 128
    if (tid < 128) shh[tid] = attn_hT[tid * 64 + b];
    __syncthreads();
    float2 a2; a2.x = shh[2 * lane]; a2.y = shh[2 * lane + 1];
    for (int ni = 0; ni < 32; ni++) {
      int n = w * 32 + ni;
      float2 wv2 = *(const float2*)(sh + w * 4096 + ni * 128 + 2 * lane);
      float s = a2.x * wv2.x + a2.y * wv2.y;
      for (int off = 32; off > 0; off >>= 1) s += __shfl_xor(s, off, 64);
      if (lane == 0) pqs[n] = s + pqc[n];
    }
    __syncthreads();
    float2 p = *(const float2*)(pqs + 2 * lane);
    float2 v2 = *(const float2*)(v_w + 2 * lane);
    const int tb = tch * 128 + w * 32;
    const float* erow = esp + ((size_t)b * 1024 + tb) * 128 + 2 * lane;
    for (int i2 = 0; i2 < 8; i2++) {
      const float* er = erow + (size_t)i2 * 512;
      float2 e0 = *(const float2*)(er);
      float2 e1 = *(const float2*)(er + 128);
      float2 e2 = *(const float2*)(er + 256);
      float2 e3 = *(const float2*)(er + 384);
      float s0 = v2.x * tanh_f(p.x + e0.x) + v2.y * tanh_f(p.y + e0.y);
      float s1 = v2.x * tanh_f(p.x + e1.x) + v2.y * tanh_f(p.y + e1.y);
      float s2 = v2.x * tanh_f(p.x + e2.x) + v2.y * tanh_f(p.y + e2.y);
      float s3 = v2.x * tanh_f(p.x + e3.x) + v2.y * tanh_f(p.y + e3.y);
      for (int off = 32; off > 0; off >>= 1) {
        s0 += __shfl_down(s0, off, 64);
        s1 += __shfl_down(s1, off, 64);
        s2 += __shfl_down(s2, off, 64);
        s3 += __shfl_down(s3, off, 64);
      }
      if (lane == 0) {
        int t = tb + i2 * 4;
        stw(&u_buf[b * 1024 + t],     (chars[b * 1024 + t]     != 0) ? s0 : 0.0f);
        stw(&u_buf[b * 1024 + t + 1], (chars[b * 1024 + t + 1] != 0) ? s1 : 0.0f);
        stw(&u_buf[b * 1024 + t + 2], (chars[b * 1024 + t + 2] != 0) ? s2 : 0.0f);
        stw(&u_buf[b * 1024 + t + 3], (chars[b * 1024 + t + 3] != 0) ? s3 : 0.0f);
      }
    }
  }
  gbar(ibase, 4);

  // ---------------- P5: softmax + context partials -> atomicAdd ctxT ----------------
  {
    const int b = g >> 3, tch = g & 7;
    float* redm = sh;          // 256
    float* sc   = sh + 256;    // 128
    float* red4 = sh + 384;    // 2048
    float4 uv = *(const float4*)(u_buf + b * 1024 + tid * 4);
    float m = fmaxf(fmaxf(uv.x, uv.y), fmaxf(uv.z, uv.w));
    redm[tid] = m;
    __syncthreads();
    for (int s = 128; s > 0; s >>= 1) { if (tid < s) redm[tid] = fmaxf(redm[tid], redm[tid + s]); __syncthreads(); }
    float M = redm[0];
    __syncthreads();
    float e0 = __expf(uv.x - M), e1 = __expf(uv.y - M), e2 = __expf(uv.z - M), e3 = __expf(uv.w - M);
    redm[tid] = e0 + e1 + e2 + e3;
    __syncthreads();
    for (int s = 128; s > 0; s >>= 1) { if (tid < s) redm[tid] += redm[tid + s]; __syncthreads(); }
    float inv = 1.0f / redm[0];
    if (tch == 0) {
      float4 r; r.x = e0 * inv; r.y = e1 * inv; r.z = e2 * inv; r.w = e3 * inv;
      *(float4*)(scores_o + b * 1024 + tid * 4) = r;
    }
    if (tid < 128) sc[tid] = __expf(u_buf[b * 1024 + tch * 128 + tid] - M) * inv;
    __syncthreads();
    float acc0 = 0, acc1 = 0, acc2 = 0, acc3 = 0, acc4 = 0, acc5 = 0, acc6 = 0, acc7 = 0;
    const float* base = es + ((size_t)b * 1024 + tch * 128) * 512 + lane * 8;
    for (int i = 0; i < 32; i += 2) {
      int t1 = 4 * i + w, t2 = t1 + 4;
      float4 wa1 = *(const float4*)(base + (size_t)t1 * 512);
      float4 wb1 = *(const float4*)(base + (size_t)t1 * 512 + 4);
      float4 wa2 = *(const float4*)(base + (size_t)t2 * 512);
      float4 wb2 = *(const float4*)(base + (size_t)t2 * 512 + 4);
      float s1 = sc[t1], s2 = sc[t2];
      acc0 += s1 * wa1.x + s2 * wa2.x; acc1 += s1 * wa1.y + s2 * wa2.y;
      acc2 += s1 * wa1.z + s2 * wa2.z; acc3 += s1 * wa1.w + s2 * wa2.w;
      acc4 += s1 * wb1.x + s2 * wb2.x; acc5 += s1 * wb1.y + s2 * wb2.y;
      acc6 += s1 * wb1.z + s2 * wb2.z; acc7 += s1 * wb1.w + s2 * wb2.w;
    }
    float* rr = red4 + w * 512 + lane * 8;
    rr[0] = acc0; rr[1] = acc1; rr[2] = acc2; rr[3] = acc3;
    rr[4] = acc4; rr[5] = acc5; rr[6] = acc6; rr[7] = acc7;
    __syncthreads();
    int d0 = tid * 2;
    float r0 = red4[d0] + red4[512 + d0] + red4[1024 + d0] + red4[1536 + d0];
    float r1 = red4[d0 + 1] + red4[512 + d0 + 1] + red4[1024 + d0 + 1] + red4[1536 + d0 + 1];
    atomicAdd(&ctxT[d0 * 64 + b], r0);
    atomicAdd(&ctxT[(d0 + 1) * 64 + b], r1);
  }
  gbar(ibase, 5);

  // ---------------- P6: xT = concat(ctx, attn_h) @ ri_w.T + ri_b ; ctx_o ----------------
  {
    const int n = g;
    if (tid < 160) ((float4*)sh)[tid] = ((const float4*)(ri_w + (size_t)n * 640))[tid];
    if (tid < 64) ctx_o[tid * 512 + n] = ctxT[n * 64 + tid];
    __syncthreads();
    const int k0 = w * 160;
    float acc = 0.0f;
    for (int k = k0; k < k0 + 160; k += 2) {
      float2 wv2 = *(const float2*)(sh + k);
      float x0 = (k < 512) ? ctxT[k * 64 + lane] : attn_hT[(k - 512) * 64 + lane];
      float x1 = (k + 1 < 512) ? ctxT[(k + 1) * 64 + lane] : attn_hT[(k - 511) * 64 + lane];
      acc += x0 * wv2.x + x1 * wv2.y;
    }
    sh[640 + w * 64 + lane] = acc;
    __syncthreads();
    if (tid < 64) stw(&xT[n * 64 + tid], ri_b[n] + sh[640 + tid] + sh[704 + tid] + sh[768 + tid] + sh[832 + tid]);
  }
  gbar(ibase, 6);

  // ---------------- P7: LSTM1 mm + gates fused (wave w -> row g+512w) ----------------
  {
    const int n = g + (w << 9);
    {
      const float4* si = (const float4*)(l1_w_ih + (size_t)n * 512);
      const float4* sh4 = (const float4*)(l1_w_hh + (size_t)n * 512);
      float4* di = (float4*)(sh + w * 1024);
      float4* dh = (float4*)(sh + w * 1024 + 512);
      #pragma unroll
      for (int q = 0; q < 2; q++) { di[q * 64 + lane] = si[q * 64 + lane]; dh[q * 64 + lane] = sh4[q * 64 + lane]; }
    }
    __syncthreads();
    float acc = l1_b_ih[n] + l1_b_hh[n];
    #pragma unroll 4
    for (int k = 0; k < 512; k += 2) {
      float2 wv2 = *(const float2*)(sh + w * 1024 + k);
      acc += xT[k * 64 + lane] * wv2.x + xT[(k + 1) * 64 + lane] * wv2.y;
    }
    #pragma unroll 4
    for (int k = 0; k < 512; k += 2) {
      float2 wv2 = *(const float2*)(sh + w * 1024 + 512 + k);
      acc += h1pT[k * 64 + lane] * wv2.x + h1pT[(k + 1) * 64 + lane] * wv2.y;
    }
    sh[4096 + w * 64 + lane] = acc;
    __syncthreads();
    if (tid < 64) {
      float gi = sh[4096 + tid], gf = sh[4160 + tid], gg = sh[4224 + tid], go = sh[4288 + tid];
      float c = c1pT[g * 64 + tid];
      float c2 = sigm(gf) * c + sigm(gi) * tanh_f(gg);
      float h2v = sigm(go) * tanh_f(c2);
      h1_o[tid * 512 + g] = h2v;
      c1_o[tid * 512 + g] = c2;
      stw(&x2T[g * 64 + tid], xT[g * 64 + tid] + h2v);
    }
  }
  gbar(ibase, 7);

  // ---------------- P8: LSTM2 mm + gates fused ----------------
  {
    const int n = g + (w << 9);
    {
      const float4* si = (const float4*)(l2_w_ih + (size_t)n * 512);
      const float4* sh4 = (const float4*)(l2_w_hh + (size_t)n * 512);
      float4* di = (float4*)(sh + w * 1024);
      float4* dh = (float4*)(sh + w * 1024 + 512);
      #pragma unroll
      for (int q = 0; q < 2; q++) { di[q * 64 + lane] = si[q * 64 + lane]; dh[q * 64 + lane] = sh4[q * 64 + lane]; }
    }
    __syncthreads();
    float acc = l2_b_ih[n] + l2_b_hh[n];
    #pragma unroll 4
    for (int k = 0; k < 512; k += 2) {
      float2 wv2 = *(const float2*)(sh + w * 1024 + k);
      acc += x2T[k * 64 + lane] * wv2.x + x2T[(k + 1) * 64 + lane] * wv2.y;
    }
    #pragma unroll 4
    for (int k = 0; k < 512; k += 2) {
      float2 wv2 = *(const float2*)(sh + w * 1024 + 512 + k);
      acc += h2pT[k * 64 + lane] * wv2.x + h2pT[(k + 1) * 64 + lane] * wv2.y;
    }
    sh[4096 + w * 64 + lane] = acc;
    __syncthreads();
    if (tid < 64) {
      float gi = sh[4096 + tid], gf = sh[4160 + tid], gg = sh[4224 + tid], go = sh[4288 + tid];
      float c = c2pT[g * 64 + tid];
      float c2 = sigm(gf) * c + sigm(gi) * tanh_f(gg);
      float h2v = sigm(go) * tanh_f(c2);
      h2_o[tid * 512 + g] = h2v;
      c2_o[tid * 512 + g] = c2;
      stw(&x3T[g * 64 + tid], x2T[g * 64 + tid] + h2v);
    }
  }
  gbar(ibase, 8);

  // ---------------- P9: mels + stop ----------------
  if (g < 20) {
    #pragma unroll
    for (int q = 0; q < 2; q++) {
      int idx = q * 256 + tid;           // 0..511 float4s
      int j = idx >> 7, c = idx & 127;
      ((float4*)sh)[idx] = ((const float4*)(mp_w + (size_t)(g * 4 + j) * 20 * 512))[c];
    }
    __syncthreads();
    float acc0 = 0, acc1 = 0, acc2 = 0, acc3 = 0;
    for (int kk = 0; kk < 128; kk++) {
      int k = w * 128 + kk;
      float x3 = x3T[k * 64 + lane];
      acc0 += x3 * sh[k]; acc1 += x3 * sh[512 + k]; acc2 += x3 * sh[1024 + k]; acc3 += x3 * sh[1536 + k];
    }
    sh[2048 + w * 256 + 0 * 64 + lane] = acc0;
    sh[2048 + w * 256 + 1 * 64 + lane] = acc1;
    sh[2048 + w * 256 + 2 * 64 + lane] = acc2;
    sh[2048 + w * 256 + 3 * 64 + lane] = acc3;
    __syncthreads();
    int j = tid >> 6, ln = tid & 63;
    float s = sh[2048 + j * 64 + ln] + sh[2304 + j * 64 + ln] + sh[2560 + j * 64 + ln] + sh[2816 + j * 64 + ln];
    mels_o[ln * 80 + g * 4 + j] = s;
  } else if (g == 20) {
    ((float4*)sh)[tid] = ((const float4*)sp_w)[tid];   // 1024 floats
    __syncthreads();
    float acc = 0;
    for (int kk = 0; kk < 128; kk++) {
      int k = w * 128 + kk;
      acc += x3T[k * 64 + lane] * sh[k] + ctxT[k * 64 + lane] * sh[512 + k];
    }
    sh[1024 + w * 64 + lane] = acc;
    __syncthreads();
    if (tid < 64) stop_o[tid] = sigm(sp_b[0] + sh[1024 + tid] + sh[1088 + tid] + sh[1152 + tid] + sh[1216 + tid]);
  }
}

// =================================================================
extern "C" void kernel_launch(void* const* d_in, const int* in_sizes, int n_in,
                              void* d_out, int out_size, void* d_ws, size_t ws_size,
                              hipStream_t stream) {
  const float* es          = (const float*)d_in[0];
  const float* esp         = (const float*)d_in[1];
  const float* prenet_in   = (const float*)d_in[2];
  const float* attn_hidden = (const float*)d_in[3];
  const float* rnn1_hidden = (const float*)d_in[4];
  const float* rnn2_hidden = (const float*)d_in[5];
  const float* rnn1_cell   = (const float*)d_in[6];
  const float* rnn2_cell   = (const float*)d_in[7];
  const float* context_vec = (const float*)d_in[8];
  const int* chars         = (const int*)d_in[9];
  // d_in[10] = t (unused), d_in[11] = conv_w (unused: conv input is zeros)
  const float* conv_b = (const float*)d_in[12];
  const float* L_w    = (const float*)d_in[13];
  const float* W_w    = (const float*)d_in[14];
  const float* W_b    = (const float*)d_in[15];
  const float* v_w    = (const float*)d_in[16];
  const float* fc1_w  = (const float*)d_in[17];
  const float* fc1_b  = (const float*)d_in[18];
  const float* fc2_w  = (const float*)d_in[19];
  const float* fc2_b  = (const float*)d_in[20];
  const float* gru_w_ih = (const float*)d_in[21];
  const float* gru_w_hh = (const float*)d_in[22];
  const float* gru_b_ih = (const float*)d_in[23];
  const float* gru_b_hh = (const float*)d_in[24];
  const float* ri_w   = (const float*)d_in[25];
  const float* ri_b   = (const float*)d_in[26];
  const float* l1_w_ih = (const float*)d_in[27];
  const float* l1_w_hh = (const float*)d_in[28];
  const float* l1_b_ih = (const float*)d_in[29];
  const float* l1_b_hh = (const float*)d_in[30];
  const float* l2_w_ih = (const float*)d_in[31];
  const float* l2_w_hh = (const float*)d_in[32];
  const float* l2_b_ih = (const float*)d_in[33];
  const float* l2_b_hh = (const float*)d_in[34];
  const float* mp_w = (const float*)d_in[35];
  const float* sp_w = (const float*)d_in[36];
  const float* sp_b = (const float*)d_in[37];

  float* out = (float*)d_out;
  float* ws = (float*)d_ws;

  float* mels_o   = out + 0;
  float* scores_o = out + 5120;
  float* attn_o   = out + 70656;
  float* h1_o     = out + 78848;
  float* h2_o     = out + 111616;
  float* c1_o     = out + 144384;
  float* c2_o     = out + 177152;
  float* ctx_o    = out + 209920;
  float* stop_o   = out + 242688;

  k0<<<1, 256, 0, stream>>>((int*)ws);
  kM<<<NB, 256, 0, stream>>>(es, esp, prenet_in, rnn1_hidden, rnn2_hidden,
                             rnn1_cell, rnn2_cell, context_vec, attn_hidden, chars,
                             conv_b, L_w, W_w, W_b, v_w,
                             fc1_w, fc1_b, fc2_w, fc2_b,
                             gru_w_ih, gru_w_hh, gru_b_ih, gru_b_hh,
                             ri_w, ri_b,
                             l1_w_ih, l1_w_hh, l1_b_ih, l1_b_hh,
                             l2_w_ih, l2_w_hh, l2_b_ih, l2_b_hh,
                             mp_w, sp_w, sp_b,
                             ws,
                             mels_o, scores_o, attn_o, h1_o, h2_o,
                             c1_o, c2_o, ctx_o, stop_o);
}

// Round 6
// 425.575 us; speedup vs baseline: 3.0027x; 1.1450x over previous
//
#include <hip/hip_runtime.h>
#include <stdint.h>

#define JAX_PARTITIONABLE 1
#define NB 512

// ---------- helpers ----------
__device__ __forceinline__ float tanh_f(float x) {
  float e = __expf(2.0f * x);
  return 1.0f - 2.0f / (e + 1.0f);
}
__device__ __forceinline__ float sigm(float x) {
  return 1.0f / (1.0f + __expf(-x));
}

// Workspace stores: agent-scope relaxed atomic stores (sc1 write-through to the
// coherent memory side). Consumers use PLAIN loads after the barrier; first touch
// of each line is always post-barrier (write-once-then-read dataflow), hence fresh.
__device__ __forceinline__ void stw(float* p, float v) {
  __hip_atomic_store(p, v, __ATOMIC_RELAXED, __HIP_MEMORY_SCOPE_AGENT);
}
__device__ __forceinline__ void stw4(float* p, float4 v) {
  union { float2 f; uint64_t u; } a, b;
  a.f.x = v.x; a.f.y = v.y; b.f.x = v.z; b.f.y = v.w;
  __hip_atomic_store((uint64_t*)p, a.u, __ATOMIC_RELAXED, __HIP_MEMORY_SCOPE_AGENT);
  __hip_atomic_store(((uint64_t*)p) + 1, b.u, __ATOMIC_RELAXED, __HIP_MEMORY_SCOPE_AGENT);
}

// ---------- Threefry-2x32 (JAX-compatible) ----------
__device__ __forceinline__ void tf2x32(unsigned k0, unsigned k1, unsigned x0, unsigned x1,
                                       unsigned &o0, unsigned &o1) {
  unsigned ks0 = k0, ks1 = k1, ks2 = k0 ^ k1 ^ 0x1BD11BDAu;
  x0 += ks0; x1 += ks1;
#define RR(r) { x0 += x1; x1 = (x1 << r) | (x1 >> (32 - r)); x1 ^= x0; }
  RR(13) RR(15) RR(26) RR(6)  x0 += ks1; x1 += ks2 + 1u;
  RR(17) RR(29) RR(16) RR(24) x0 += ks2; x1 += ks0 + 2u;
  RR(13) RR(15) RR(26) RR(6)  x0 += ks0; x1 += ks1 + 3u;
  RR(17) RR(29) RR(16) RR(24) x0 += ks1; x1 += ks2 + 4u;
  RR(13) RR(15) RR(26) RR(6)  x0 += ks2; x1 += ks0 + 5u;
#undef RR
  o0 = x0; o1 = x1;
}

__device__ __forceinline__ float drop_scale(unsigned k0, unsigned k1, unsigned flat) {
#if JAX_PARTITIONABLE
  unsigned o0, o1; tf2x32(k0, k1, 0u, flat, o0, o1);
  unsigned bits = o0 ^ o1;
#else
  unsigned o0, o1, bits;
  if (flat < 8192u) { tf2x32(k0, k1, flat, flat + 8192u, o0, o1); bits = o0; }
  else             { tf2x32(k0, k1, flat - 8192u, flat, o0, o1); bits = o1; }
#endif
  return (bits >> 31) ? 0.0f : 2.0f;
}
__device__ __forceinline__ void get_drop_keys(unsigned &a0, unsigned &a1,
                                              unsigned &b0, unsigned &b1) {
#if JAX_PARTITIONABLE
  tf2x32(0u, 42u, 0u, 0u, a0, a1);
  tf2x32(0u, 42u, 0u, 1u, b0, b1);
#else
  unsigned p0, q0, p1, q1;
  tf2x32(0u, 42u, 0u, 2u, p0, q0);
  tf2x32(0u, 42u, 1u, 3u, p1, q1);
  a0 = p0; a1 = p1; b0 = q0; b1 = q1;
#endif
}

// ---------- fence-free device barrier (R4 design, unchanged) ----------
__device__ __forceinline__ void gbar(int* ibase, int phase) {
  __syncthreads();
  if (threadIdx.x == 0) {
    const int s = (int)(blockIdx.x & 15);
    int* sub   = ibase + s * 64;
    int* top   = ibase + 1024;
    int* flags = ibase + 1088;
    int old = __hip_atomic_fetch_add(sub, 1, __ATOMIC_RELAXED, __HIP_MEMORY_SCOPE_AGENT);
    if (old == phase * 32 - 1) {
      int t = __hip_atomic_fetch_add(top, 1, __ATOMIC_RELAXED, __HIP_MEMORY_SCOPE_AGENT);
      if (t == phase * 16 - 1) {
        #pragma unroll
        for (int i = 0; i < 16; i++)
          __hip_atomic_store(flags + i * 64, phase, __ATOMIC_RELAXED, __HIP_MEMORY_SCOPE_AGENT);
      }
    }
    long long guard = 0;
    while (__hip_atomic_load(flags + s * 64, __ATOMIC_RELAXED, __HIP_MEMORY_SCOPE_AGENT) < phase) {
      __builtin_amdgcn_s_sleep(4);
      if (++guard > (1LL << 21)) break;
    }
  }
  __syncthreads();
}

// =================================================================
// k0: zero barrier counters + flags (ws is poisoned between iterations)
// =================================================================
__global__ void k0(int* cnt) {
  for (int i = threadIdx.x; i < 2112; i += 256) cnt[i] = 0;
}

// =================================================================
// kM: whole decoder step, 9 phases / 8 grid barriers
// Activations packed as [k/4][b][4]: lane b loads float4 of 4 consecutive k.
// =================================================================
__global__ __launch_bounds__(256, 2) void kM(
    const float* es, const float* esp, const float* prenet_in,
    const float* rnn1_hidden, const float* rnn2_hidden,
    const float* rnn1_cell, const float* rnn2_cell,
    const float* context_vec, const float* attn_hidden, const int* chars,
    const float* conv_b, const float* L_w, const float* W_w, const float* W_b, const float* v_w,
    const float* fc1_w, const float* fc1_b, const float* fc2_w, const float* fc2_b,
    const float* gru_w_ih, const float* gru_w_hh, const float* gru_b_ih, const float* gru_b_hh,
    const float* ri_w, const float* ri_b,
    const float* l1_w_ih, const float* l1_w_hh, const float* l1_b_ih, const float* l1_b_hh,
    const float* l2_w_ih, const float* l2_w_hh, const float* l2_b_ih, const float* l2_b_hh,
    const float* mp_w, const float* sp_w, const float* sp_b,
    float* ws,
    float* mels_o, float* scores_o, float* attn_o, float* h1_o, float* h2_o,
    float* c1_o, float* c2_o, float* ctx_o, float* stop_o) {
  int* ibase = (int*)ws;            // 2112 ints
  float* pqc    = ws + 2112;        // 128
  float* phq    = ws + 2240;        // 16384  [64][64][4]
  float* poq    = ws + 18624;       // 16384  [64][64][4]
  float* ahq_h  = ws + 35008;       // 8192   [32][64][4]  attn_h (GRU out)
  float* u_buf  = ws + 43200;       // 65536
  float* ctxq   = ws + 108736;      // 32768  [128][64][4] (atomic-accum; zeroed P1)
  float* xq     = ws + 141504;      // 32768  [128][64][4]
  float* x2q    = ws + 174272;      // 32768
  float* x3q    = ws + 207040;      // 32768
  float* hq1    = ws + 239808;      // 32768  rnn1_hidden packed
  float* hq2    = ws + 272576;      // 32768
  float* cvq    = ws + 305344;      // 32768  context_vec packed
  float* ahq_in = ws + 338112;      // 8192   attn_hidden packed
  float* c1pT   = ws + 346304;      // 32768  [k][b] (unpacked; read per-k contiguous)
  float* c2pT   = ws + 379072;      // 32768

  const float4* cvq4   = (const float4*)cvq;
  const float4* phq4   = (const float4*)phq;
  const float4* poq4   = (const float4*)poq;
  const float4* ahq_in4= (const float4*)ahq_in;
  const float4* ahq_h4 = (const float4*)ahq_h;
  const float4* ctxq4  = (const float4*)ctxq;
  const float4* xq4    = (const float4*)xq;
  const float4* x2q4   = (const float4*)x2q;
  const float4* x3q4   = (const float4*)x3q;
  const float4* hq14   = (const float4*)hq1;
  const float4* hq24   = (const float4*)hq2;

  const int g = blockIdx.x, tid = threadIdx.x;
  const int w = tid >> 6, lane = tid & 63;
  __shared__ float sh[16640];       // 66.5 KB -> 2 blocks/CU

  // ---------------- P1: fc1 + packed transposes + zero ctxq + pqc + warm(es part A) ----------------
  if (g < 64) {
    for (int i = tid; i < 5120; i += 256) sh[(i / 80) * 81 + (i % 80)] = prenet_in[i];
    __syncthreads();
    unsigned d1k0, d1k1, d2k0, d2k1;
    get_drop_keys(d1k0, d1k1, d2k0, d2k1);
    const int j = g * 4 + w;
    float acc = fc1_b[j];
    const float* wr = fc1_w + j * 80;
    #pragma unroll 8
    for (int k = 0; k < 80; k += 2) {
      float2 wv = *(const float2*)(wr + k);
      acc += sh[lane * 81 + k] * wv.x + sh[lane * 81 + k + 1] * wv.y;
    }
    acc = fmaxf(acc, 0.0f) * drop_scale(d1k0, d1k1, (unsigned)(lane * 256 + j));
    stw(&phq[g * 256 + lane * 4 + w], acc);   // j>>2 = g, j&3 = w
  } else if (g < 96) {          // hq1: 32 blocks
    int t = (g - 64) * 256 + tid;             // 0..8191
    int k4 = t >> 6, b = t & 63;
    stw4(&hq1[k4 * 256 + b * 4], ((const float4*)rnn1_hidden)[b * 128 + k4]);
  } else if (g < 128) {         // hq2
    int t = (g - 96) * 256 + tid;
    int k4 = t >> 6, b = t & 63;
    stw4(&hq2[k4 * 256 + b * 4], ((const float4*)rnn2_hidden)[b * 128 + k4]);
  } else if (g < 160) {         // cvq
    int t = (g - 128) * 256 + tid;
    int k4 = t >> 6, b = t & 63;
    stw4(&cvq[k4 * 256 + b * 4], ((const float4*)context_vec)[b * 128 + k4]);
  } else if (g < 168) {         // ahq_in: 8 blocks
    int t = (g - 160) * 256 + tid;            // 0..2047
    int k4 = t >> 6, b = t & 63;
    stw4(&ahq_in[k4 * 256 + b * 4], ((const float4*)attn_hidden)[b * 32 + k4]);
  } else if (g < 232) {         // c1pT [k][b]
    int base = (g - 168) * 512;
    #pragma unroll
    for (int e = 0; e < 2; e++) { int i = base + tid + e * 256; stw(&c1pT[i], rnn1_cell[(i & 63) * 512 + (i >> 6)]); }
  } else if (g < 296) {         // c2pT
    int base = (g - 232) * 512;
    #pragma unroll
    for (int e = 0; e < 2; e++) { int i = base + tid + e * 256; stw(&c2pT[i], rnn2_cell[(i & 63) * 512 + (i >> 6)]); }
  } else if (g < 360) {         // zero ctxq
    int base = (g - 296) * 512;
    #pragma unroll
    for (int e = 0; e < 2; e++) stw(&ctxq[base + tid + e * 256], 0.0f);
  } else if (g == 360) {        // pqc
    if (tid < 128) {
      float acc = W_b[tid];
      const float* lw = L_w + tid * 32;
      #pragma unroll
      for (int f = 0; f < 32; f++) acc += conv_b[f] * lw[f];
      stw(&pqc[tid], acc);
    }
  } else {                      // warm es part A: lines 0..386559 (151 blocks)
    const unsigned wi0 = (unsigned)((g - 361) * 256 + tid);   // 0..38655
    float acc = 0.0f;
    #pragma unroll
    for (int s = 0; s < 10; s++) acc += es[(size_t)(wi0 + (unsigned)s * 38656u) * 32];
    asm volatile("" :: "v"(acc));
  }
  gbar(ibase, 1);

  // ---------------- P2: fc2 (LDS weights, packed phq) | warm es part B ----------------
  if (g < 64) {
    const int j = g * 4 + w;
    ((float4*)(sh + w * 256))[lane] = ((const float4*)(fc2_w + j * 256))[lane];
    __syncthreads();
    unsigned d1k0, d1k1, d2k0, d2k1;
    get_drop_keys(d1k0, d1k1, d2k0, d2k1);
    const float4* wv4 = (const float4*)(sh + w * 256);
    float acc = fc2_b[j];
    #pragma unroll 8
    for (int k4 = 0; k4 < 64; k4++) {
      float4 x4 = phq4[k4 * 64 + lane];
      float4 wv = wv4[k4];
      acc += x4.x * wv.x + x4.y * wv.y + x4.z * wv.z + x4.w * wv.w;
    }
    acc = fmaxf(acc, 0.0f) * drop_scale(d2k0, d2k1, (unsigned)(lane * 256 + j));
    stw(&poq[g * 256 + lane * 4 + w], acc);
  } else {
    // warm es lines 386560..1048575 (448 blocks x 256 thr x 6)
    const unsigned wi0 = (unsigned)((g - 64) * 256 + tid);
    float acc = 0.0f;
    #pragma unroll
    for (int s = 0; s < 6; s++) {
      unsigned idx = 386560u + wi0 + (unsigned)s * 114688u;
      if (idx < 1048576u) acc += es[(size_t)idx * 32];
    }
    asm volatile("" :: "v"(acc));
  }
  gbar(ibase, 2);

  // ---------------- P3: GRU mm + gates fused (blocks 0-127) | warm esp/W_w/chars ----------------
  if (g < 128) {
    if (w < 3) {
      const int rj = g + 128 * w;
      const float4* src = (const float4*)(gru_w_ih + (size_t)rj * 768);
      float4* dst = (float4*)(sh + w * 768);
      #pragma unroll
      for (int q = 0; q < 3; q++) dst[q * 64 + lane] = src[q * 64 + lane];
    } else {
      float4* dst = (float4*)(sh + 2304);
      if (lane < 32) {
        dst[lane]      = ((const float4*)gru_w_hh)[(size_t)g * 32 + lane];
        dst[32 + lane] = ((const float4*)gru_w_hh)[(size_t)(128 + g) * 32 + lane];
        dst[64 + lane] = ((const float4*)gru_w_hh)[(size_t)(256 + g) * 32 + lane];
      }
    }
    __syncthreads();
    if (w < 3) {
      const int rj = g + 128 * w;
      const float4* wv4 = (const float4*)(sh + w * 768);
      float acc = gru_b_ih[rj];
      #pragma unroll 4
      for (int k4 = 0; k4 < 128; k4++) {
        float4 x4 = cvq4[k4 * 64 + lane];
        float4 wv = wv4[k4];
        acc += x4.x * wv.x + x4.y * wv.y + x4.z * wv.z + x4.w * wv.w;
      }
      #pragma unroll 4
      for (int k4 = 0; k4 < 64; k4++) {
        float4 x4 = poq4[k4 * 64 + lane];
        float4 wv = wv4[128 + k4];
        acc += x4.x * wv.x + x4.y * wv.y + x4.z * wv.z + x4.w * wv.w;
      }
      sh[2688 + w * 64 + lane] = acc;
    } else {
      const float4* wh4 = (const float4*)(sh + 2304);
      #pragma unroll
      for (int r = 0; r < 3; r++) {
        float acc = gru_b_hh[r * 128 + g];
        #pragma unroll 4
        for (int k4 = 0; k4 < 32; k4++) {
          float4 x4 = ahq_in4[k4 * 64 + lane];
          float4 wv = wh4[r * 32 + k4];
          acc += x4.x * wv.x + x4.y * wv.y + x4.z * wv.z + x4.w * wv.w;
        }
        sh[2688 + (3 + r) * 64 + lane] = acc;
      }
    }
    __syncthreads();
    if (tid < 64) {
      float gr = sh[2688 + tid]       + sh[2688 + 192 + tid];
      float gz = sh[2688 + 64 + tid]  + sh[2688 + 256 + tid];
      float gin = sh[2688 + 128 + tid];
      float ghn = sh[2688 + 320 + tid];
      float a0 = ahq_in[(g >> 2) * 256 + tid * 4 + (g & 3)];
      float r = sigm(gr), z = sigm(gz);
      float h = (1.0f - z) * tanh_f(gin + r * ghn) + z * a0;
      stw(&ahq_h[(g >> 2) * 256 + tid * 4 + (g & 3)], h);
      attn_o[tid * 128 + g] = h;
    }
  } else {
    const unsigned wi0 = (unsigned)((g - 128) * 256 + tid);
    float acc = 0.0f;
    #pragma unroll
    for (int s = 0; s < 3; s++) {
      unsigned idx = wi0 + (unsigned)s * 98304u;
      if (idx < 262144u) acc += esp[(size_t)idx * 32];
    }
    if (g == 128) { if (tid < 512) acc += W_w[tid * 32]; }
    if (g == 129) {
      #pragma unroll
      for (int s = 0; s < 8; s++) acc += (float)chars[(tid + s * 256) * 32];
    }
    asm volatile("" :: "v"(acc));
  }
  gbar(ibase, 3);

  // ---------------- P4: pq (LDS W_w) + u ----------------
  {
    const int b = g >> 3, tch = g & 7;
    {
      const float4* src = ((const float4*)W_w) + (size_t)(w * 32) * 32;
      float4* dst = (float4*)sh + w * 1024;
      #pragma unroll
      for (int q = 0; q < 16; q++) dst[q * 64 + lane] = src[q * 64 + lane];
    }
    float* pqs = sh + 16384;   // 128
    float* shh = sh + 16512;   // 128
    if (tid < 128) shh[tid] = ahq_h[(tid >> 2) * 256 + b * 4 + (tid & 3)];
    __syncthreads();
    float2 a2; a2.x = shh[2 * lane]; a2.y = shh[2 * lane + 1];
    for (int ni = 0; ni < 32; ni++) {
      int n = w * 32 + ni;
      float2 wv2 = *(const float2*)(sh + w * 4096 + ni * 128 + 2 * lane);
      float s = a2.x * wv2.x + a2.y * wv2.y;
      for (int off = 32; off > 0; off >>= 1) s += __shfl_xor(s, off, 64);
      if (lane == 0) pqs[n] = s + pqc[n];
    }
    __syncthreads();
    float2 p = *(const float2*)(pqs + 2 * lane);
    float2 v2 = *(const float2*)(v_w + 2 * lane);
    const int tb = tch * 128 + w * 32;
    const float* erow = esp + ((size_t)b * 1024 + tb) * 128 + 2 * lane;
    for (int i2 = 0; i2 < 8; i2++) {
      const float* er = erow + (size_t)i2 * 512;
      float2 e0 = *(const float2*)(er);
      float2 e1 = *(const float2*)(er + 128);
      float2 e2 = *(const float2*)(er + 256);
      float2 e3 = *(const float2*)(er + 384);
      float s0 = v2.x * tanh_f(p.x + e0.x) + v2.y * tanh_f(p.y + e0.y);
      float s1 = v2.x * tanh_f(p.x + e1.x) + v2.y * tanh_f(p.y + e1.y);
      float s2 = v2.x * tanh_f(p.x + e2.x) + v2.y * tanh_f(p.y + e2.y);
      float s3 = v2.x * tanh_f(p.x + e3.x) + v2.y * tanh_f(p.y + e3.y);
      for (int off = 32; off > 0; off >>= 1) {
        s0 += __shfl_down(s0, off, 64);
        s1 += __shfl_down(s1, off, 64);
        s2 += __shfl_down(s2, off, 64);
        s3 += __shfl_down(s3, off, 64);
      }
      if (lane == 0) {
        int t = tb + i2 * 4;
        stw(&u_buf[b * 1024 + t],     (chars[b * 1024 + t]     != 0) ? s0 : 0.0f);
        stw(&u_buf[b * 1024 + t + 1], (chars[b * 1024 + t + 1] != 0) ? s1 : 0.0f);
        stw(&u_buf[b * 1024 + t + 2], (chars[b * 1024 + t + 2] != 0) ? s2 : 0.0f);
        stw(&u_buf[b * 1024 + t + 3], (chars[b * 1024 + t + 3] != 0) ? s3 : 0.0f);
      }
    }
  }
  gbar(ibase, 4);

  // ---------------- P5: softmax + context partials -> atomicAdd ctxq ----------------
  {
    const int b = g >> 3, tch = g & 7;
    float* redm = sh;          // 256
    float* sc   = sh + 256;    // 128
    float* red4 = sh + 384;    // 2048
    float4 uv = *(const float4*)(u_buf + b * 1024 + tid * 4);
    float m = fmaxf(fmaxf(uv.x, uv.y), fmaxf(uv.z, uv.w));
    redm[tid] = m;
    __syncthreads();
    for (int s = 128; s > 0; s >>= 1) { if (tid < s) redm[tid] = fmaxf(redm[tid], redm[tid + s]); __syncthreads(); }
    float M = redm[0];
    __syncthreads();
    float e0 = __expf(uv.x - M), e1 = __expf(uv.y - M), e2 = __expf(uv.z - M), e3 = __expf(uv.w - M);
    redm[tid] = e0 + e1 + e2 + e3;
    __syncthreads();
    for (int s = 128; s > 0; s >>= 1) { if (tid < s) redm[tid] += redm[tid + s]; __syncthreads(); }
    float inv = 1.0f / redm[0];
    if (tch == 0) {
      float4 r; r.x = e0 * inv; r.y = e1 * inv; r.z = e2 * inv; r.w = e3 * inv;
      *(float4*)(scores_o + b * 1024 + tid * 4) = r;
    }
    if (tid < 128) sc[tid] = __expf(u_buf[b * 1024 + tch * 128 + tid] - M) * inv;
    __syncthreads();
    float acc0 = 0, acc1 = 0, acc2 = 0, acc3 = 0, acc4 = 0, acc5 = 0, acc6 = 0, acc7 = 0;
    const float* base = es + ((size_t)b * 1024 + tch * 128) * 512 + lane * 8;
    for (int i = 0; i < 32; i += 2) {
      int t1 = 4 * i + w, t2 = t1 + 4;
      float4 wa1 = *(const float4*)(base + (size_t)t1 * 512);
      float4 wb1 = *(const float4*)(base + (size_t)t1 * 512 + 4);
      float4 wa2 = *(const float4*)(base + (size_t)t2 * 512);
      float4 wb2 = *(const float4*)(base + (size_t)t2 * 512 + 4);
      float s1 = sc[t1], s2 = sc[t2];
      acc0 += s1 * wa1.x + s2 * wa2.x; acc1 += s1 * wa1.y + s2 * wa2.y;
      acc2 += s1 * wa1.z + s2 * wa2.z; acc3 += s1 * wa1.w + s2 * wa2.w;
      acc4 += s1 * wb1.x + s2 * wb2.x; acc5 += s1 * wb1.y + s2 * wb2.y;
      acc6 += s1 * wb1.z + s2 * wb2.z; acc7 += s1 * wb1.w + s2 * wb2.w;
    }
    float* rr = red4 + w * 512 + lane * 8;
    rr[0] = acc0; rr[1] = acc1; rr[2] = acc2; rr[3] = acc3;
    rr[4] = acc4; rr[5] = acc5; rr[6] = acc6; rr[7] = acc7;
    __syncthreads();
    int d0 = tid * 2;
    float r0 = red4[d0] + red4[512 + d0] + red4[1024 + d0] + red4[1536 + d0];
    float r1 = red4[d0 + 1] + red4[512 + d0 + 1] + red4[1024 + d0 + 1] + red4[1536 + d0 + 1];
    atomicAdd(&ctxq[(d0 >> 2) * 256 + b * 4 + (d0 & 3)], r0);
    atomicAdd(&ctxq[((d0 + 1) >> 2) * 256 + b * 4 + ((d0 + 1) & 3)], r1);
  }
  gbar(ibase, 5);

  // ---------------- P6: x = concat(ctx, attn_h) @ ri_w.T + ri_b ; ctx_o ----------------
  {
    const int n = g;
    if (tid < 160) ((float4*)sh)[tid] = ((const float4*)(ri_w + (size_t)n * 640))[tid];
    if (tid < 64) ctx_o[tid * 512 + n] = ctxq[(n >> 2) * 256 + tid * 4 + (n & 3)];
    __syncthreads();
    float acc = 0.0f;
    for (int k4 = w * 40; k4 < w * 40 + 40; k4++) {
      float4 wv = ((float4*)sh)[k4];
      float4 x4 = (k4 < 128) ? ctxq4[k4 * 64 + lane] : ahq_h4[(k4 - 128) * 64 + lane];
      acc += x4.x * wv.x + x4.y * wv.y + x4.z * wv.z + x4.w * wv.w;
    }
    sh[640 + w * 64 + lane] = acc;
    __syncthreads();
    if (tid < 64) stw(&xq[(n >> 2) * 256 + tid * 4 + (n & 3)],
                      ri_b[n] + sh[640 + tid] + sh[704 + tid] + sh[768 + tid] + sh[832 + tid]);
  }
  gbar(ibase, 6);

  // ---------------- P7: LSTM1 mm + gates fused (wave w -> row g+512w) ----------------
  {
    const int n = g + (w << 9);
    {
      const float4* si = (const float4*)(l1_w_ih + (size_t)n * 512);
      const float4* sh4 = (const float4*)(l1_w_hh + (size_t)n * 512);
      float4* di = (float4*)sh + w * 256;
      float4* dh = di + 128;
      #pragma unroll
      for (int q = 0; q < 2; q++) { di[q * 64 + lane] = si[q * 64 + lane]; dh[q * 64 + lane] = sh4[q * 64 + lane]; }
    }
    __syncthreads();
    const float4* di = (const float4*)sh + w * 256;
    const float4* dh = di + 128;
    float acc = l1_b_ih[n] + l1_b_hh[n];
    #pragma unroll 4
    for (int k4 = 0; k4 < 128; k4++) {
      float4 x4 = xq4[k4 * 64 + lane];
      float4 wv = di[k4];
      acc += x4.x * wv.x + x4.y * wv.y + x4.z * wv.z + x4.w * wv.w;
    }
    #pragma unroll 4
    for (int k4 = 0; k4 < 128; k4++) {
      float4 x4 = hq14[k4 * 64 + lane];
      float4 wv = dh[k4];
      acc += x4.x * wv.x + x4.y * wv.y + x4.z * wv.z + x4.w * wv.w;
    }
    sh[4096 + w * 64 + lane] = acc;
    __syncthreads();
    if (tid < 64) {
      float gi = sh[4096 + tid], gf = sh[4160 + tid], gg = sh[4224 + tid], go = sh[4288 + tid];
      float c = c1pT[g * 64 + tid];
      float c2 = sigm(gf) * c + sigm(gi) * tanh_f(gg);
      float h2v = sigm(go) * tanh_f(c2);
      h1_o[tid * 512 + g] = h2v;
      c1_o[tid * 512 + g] = c2;
      stw(&x2q[(g >> 2) * 256 + tid * 4 + (g & 3)],
          xq[(g >> 2) * 256 + tid * 4 + (g & 3)] + h2v);
    }
  }
  gbar(ibase, 7);

  // ---------------- P8: LSTM2 mm + gates fused ----------------
  {
    const int n = g + (w << 9);
    {
      const float4* si = (const float4*)(l2_w_ih + (size_t)n * 512);
      const float4* sh4 = (const float4*)(l2_w_hh + (size_t)n * 512);
      float4* di = (float4*)sh + w * 256;
      float4* dh = di + 128;
      #pragma unroll
      for (int q = 0; q < 2; q++) { di[q * 64 + lane] = si[q * 64 + lane]; dh[q * 64 + lane] = sh4[q * 64 + lane]; }
    }
    __syncthreads();
    const float4* di = (const float4*)sh + w * 256;
    const float4* dh = di + 128;
    float acc = l2_b_ih[n] + l2_b_hh[n];
    #pragma unroll 4
    for (int k4 = 0; k4 < 128; k4++) {
      float4 x4 = x2q4[k4 * 64 + lane];
      float4 wv = di[k4];
      acc += x4.x * wv.x + x4.y * wv.y + x4.z * wv.z + x4.w * wv.w;
    }
    #pragma unroll 4
    for (int k4 = 0; k4 < 128; k4++) {
      float4 x4 = hq24[k4 * 64 + lane];
      float4 wv = dh[k4];
      acc += x4.x * wv.x + x4.y * wv.y + x4.z * wv.z + x4.w * wv.w;
    }
    sh[4096 + w * 64 + lane] = acc;
    __syncthreads();
    if (tid < 64) {
      float gi = sh[4096 + tid], gf = sh[4160 + tid], gg = sh[4224 + tid], go = sh[4288 + tid];
      float c = c2pT[g * 64 + tid];
      float c2 = sigm(gf) * c + sigm(gi) * tanh_f(gg);
      float h2v = sigm(go) * tanh_f(c2);
      h2_o[tid * 512 + g] = h2v;
      c2_o[tid * 512 + g] = c2;
      stw(&x3q[(g >> 2) * 256 + tid * 4 + (g & 3)],
          x2q[(g >> 2) * 256 + tid * 4 + (g & 3)] + h2v);
    }
  }
  gbar(ibase, 8);

  // ---------------- P9: mels (80 blocks) + stop (1 block) ----------------
  if (g < 80) {
    const int m = g;
    if (tid < 128) ((float4*)sh)[tid] = ((const float4*)(mp_w + (size_t)m * 20 * 512))[tid];
    __syncthreads();
    float acc = 0.0f;
    for (int k4 = w * 32; k4 < w * 32 + 32; k4++) {
      float4 x4 = x3q4[k4 * 64 + lane];
      float4 wv = ((float4*)sh)[k4];
      acc += x4.x * wv.x + x4.y * wv.y + x4.z * wv.z + x4.w * wv.w;
    }
    sh[512 + w * 64 + lane] = acc;
    __syncthreads();
    if (tid < 64) mels_o[tid * 80 + m] = sh[512 + tid] + sh[576 + tid] + sh[640 + tid] + sh[704 + tid];
  } else if (g == 80) {
    ((float4*)sh)[tid] = ((const float4*)sp_w)[tid];   // 1024 floats
    __syncthreads();
    float acc = 0.0f;
    for (int k4 = w * 32; k4 < w * 32 + 32; k4++) {
      float4 x4 = x3q4[k4 * 64 + lane];
      float4 c4 = ctxq4[k4 * 64 + lane];
      float4 w1 = ((float4*)sh)[k4];
      float4 w2 = ((float4*)sh)[128 + k4];
      acc += x4.x * w1.x + x4.y * w1.y + x4.z * w1.z + x4.w * w1.w;
      acc += c4.x * w2.x + c4.y * w2.y + c4.z * w2.z + c4.w * w2.w;
    }
    sh[1024 + w * 64 + lane] = acc;
    __syncthreads();
    if (tid < 64) stop_o[tid] = sigm(sp_b[0] + sh[1024 + tid] + sh[1088 + tid] + sh[1152 + tid] + sh[1216 + tid]);
  }
}

// =================================================================
extern "C" void kernel_launch(void* const* d_in, const int* in_sizes, int n_in,
                              void* d_out, int out_size, void* d_ws, size_t ws_size,
                              hipStream_t stream) {
  const float* es          = (const float*)d_in[0];
  const float* esp         = (const float*)d_in[1];
  const float* prenet_in   = (const float*)d_in[2];
  const float* attn_hidden = (const float*)d_in[3];
  const float* rnn1_hidden = (const float*)d_in[4];
  const float* rnn2_hidden = (const float*)d_in[5];
  const float* rnn1_cell   = (const float*)d_in[6];
  const float* rnn2_cell   = (const float*)d_in[7];
  const float* context_vec = (const float*)d_in[8];
  const int* chars         = (const int*)d_in[9];
  // d_in[10] = t (unused), d_in[11] = conv_w (unused: conv input is zeros)
  const float* conv_b = (const float*)d_in[12];
  const float* L_w    = (const float*)d_in[13];
  const float* W_w    = (const float*)d_in[14];
  const float* W_b    = (const float*)d_in[15];
  const float* v_w    = (const float*)d_in[16];
  const float* fc1_w  = (const float*)d_in[17];
  const float* fc1_b  = (const float*)d_in[18];
  const float* fc2_w  = (const float*)d_in[19];
  const float* fc2_b  = (const float*)d_in[20];
  const float* gru_w_ih = (const float*)d_in[21];
  const float* gru_w_hh = (const float*)d_in[22];
  const float* gru_b_ih = (const float*)d_in[23];
  const float* gru_b_hh = (const float*)d_in[24];
  const float* ri_w   = (const float*)d_in[25];
  const float* ri_b   = (const float*)d_in[26];
  const float* l1_w_ih = (const float*)d_in[27];
  const float* l1_w_hh = (const float*)d_in[28];
  const float* l1_b_ih = (const float*)d_in[29];
  const float* l1_b_hh = (const float*)d_in[30];
  const float* l2_w_ih = (const float*)d_in[31];
  const float* l2_w_hh = (const float*)d_in[32];
  const float* l2_b_ih = (const float*)d_in[33];
  const float* l2_b_hh = (const float*)d_in[34];
  const float* mp_w = (const float*)d_in[35];
  const float* sp_w = (const float*)d_in[36];
  const float* sp_b = (const float*)d_in[37];

  float* out = (float*)d_out;
  float* ws = (float*)d_ws;

  float* mels_o   = out + 0;
  float* scores_o = out + 5120;
  float* attn_o   = out + 70656;
  float* h1_o     = out + 78848;
  float* h2_o     = out + 111616;
  float* c1_o     = out + 144384;
  float* c2_o     = out + 177152;
  float* ctx_o    = out + 209920;
  float* stop_o   = out + 242688;

  k0<<<1, 256, 0, stream>>>((int*)ws);
  kM<<<NB, 256, 0, stream>>>(es, esp, prenet_in, rnn1_hidden, rnn2_hidden,
                             rnn1_cell, rnn2_cell, context_vec, attn_hidden, chars,
                             conv_b, L_w, W_w, W_b, v_w,
                             fc1_w, fc1_b, fc2_w, fc2_b,
                             gru_w_ih, gru_w_hh, gru_b_ih, gru_b_hh,
                             ri_w, ri_b,
                             l1_w_ih, l1_w_hh, l1_b_ih, l1_b_hh,
                             l2_w_ih, l2_w_hh, l2_b_ih, l2_b_hh,
                             mp_w, sp_w, sp_b,
                             ws,
                             mels_o, scores_o, attn_o, h1_o, h2_o,
                             c1_o, c2_o, ctx_o, stop_o);
}